// Round 1
// baseline (669.902 us; speedup 1.0000x reference)
//
#include <hip/hip_runtime.h>

// ---------------- helpers ----------------
__device__ __forceinline__ unsigned fenc(float f) {
  unsigned u = __float_as_uint(f);
  return (u & 0x80000000u) ? ~u : (u | 0x80000000u);
}
__device__ __forceinline__ float fdec(unsigned e) {
  return (e & 0x80000000u) ? __uint_as_float(e & 0x7fffffffu) : __uint_as_float(~e);
}
__device__ __forceinline__ float lrelu(float x) { return x > 0.f ? x : 0.2f * x; }

// ---------------- f32 tiled GEMM: C[M,NN] = A[M,K] @ B[K,NN] ----------------
static constexpr int BM = 64, BN = 64, BKC = 64;

__global__ __launch_bounds__(256) void gemm_f32(const float* __restrict__ A,
    const float* __restrict__ B, float* __restrict__ C, int M, int NN, int K) {
  __shared__ float As[BKC][BM + 4];  // transposed: As[k][m]
  __shared__ float Bs[BKC][BN + 4];
  const int t = threadIdx.x;
  const int m0 = blockIdx.y * BM;
  const int n0 = blockIdx.x * BN;
  const int lr = t >> 4;           // 0..15
  const int lc4 = (t & 15) << 2;   // 0,4,...,60
  float acc[4][4] = {};
  for (int kk = 0; kk < K; kk += BKC) {
#pragma unroll
    for (int r = 0; r < 4; ++r) {
      int row = lr + r * 16;
      int gm = m0 + row;
      float4 v = make_float4(0.f, 0.f, 0.f, 0.f);
      if (gm < M) v = *(const float4*)&A[(size_t)gm * K + kk + lc4];
      As[lc4 + 0][row] = v.x;
      As[lc4 + 1][row] = v.y;
      As[lc4 + 2][row] = v.z;
      As[lc4 + 3][row] = v.w;
      int gk = kk + row;
      *(float4*)&Bs[row][lc4] = *(const float4*)&B[(size_t)gk * NN + n0 + lc4];
    }
    __syncthreads();
#pragma unroll
    for (int k = 0; k < BKC; ++k) {
      float4 a = *(const float4*)&As[k][lr << 2];
      float4 b = *(const float4*)&Bs[k][lc4];
      float av[4] = {a.x, a.y, a.z, a.w};
      float bv[4] = {b.x, b.y, b.z, b.w};
#pragma unroll
      for (int i = 0; i < 4; ++i)
#pragma unroll
        for (int j = 0; j < 4; ++j) acc[i][j] += av[i] * bv[j];
    }
    __syncthreads();
  }
#pragma unroll
  for (int i = 0; i < 4; ++i) {
    int gm = m0 + (lr << 2) + i;
    if (gm < M) {
      float4 o = make_float4(acc[i][0], acc[i][1], acc[i][2], acc[i][3]);
      *(float4*)&C[(size_t)gm * NN + n0 + lc4] = o;
    }
  }
}

// ---------------- per-node attention dots ----------------
__global__ __launch_bounds__(256) void alpha1_kernel(const float* __restrict__ h,
    const float* __restrict__ asrc, const float* __restrict__ adst,
    float* __restrict__ out_s, float* __restrict__ out_d, int N) {
  int wid = (blockIdx.x << 2) + (threadIdx.x >> 6);
  int lane = threadIdx.x & 63;
  if (wid >= N) return;
  const float* row = h + (size_t)wid * 256;
#pragma unroll
  for (int hh = 0; hh < 4; ++hh) {
    float v = row[hh * 64 + lane];
    float s = v * asrc[hh * 64 + lane];
    float d = v * adst[hh * 64 + lane];
#pragma unroll
    for (int off = 32; off > 0; off >>= 1) {
      s += __shfl_xor(s, off, 64);
      d += __shfl_xor(d, off, 64);
    }
    if (lane == 0) {
      out_s[wid * 4 + hh] = s;
      out_d[wid * 4 + hh] = d;
    }
  }
}

__global__ __launch_bounds__(256) void alpha2_kernel(const float* __restrict__ h,
    const float* __restrict__ asrc, const float* __restrict__ adst,
    float* __restrict__ out_s, float* __restrict__ out_d, int N) {
  int wid = (blockIdx.x << 2) + (threadIdx.x >> 6);
  int lane = threadIdx.x & 63;
  if (wid >= N) return;
  float v = h[(size_t)wid * 64 + lane];
  float s = v * asrc[lane];
  float d = v * adst[lane];
#pragma unroll
  for (int off = 32; off > 0; off >>= 1) {
    s += __shfl_xor(s, off, 64);
    d += __shfl_xor(d, off, 64);
  }
  if (lane == 0) {
    out_s[wid] = s;
    out_d[wid] = d;
  }
}

// ---------------- CSR build ----------------
__global__ void hist_kernel(const int* __restrict__ dst, int* __restrict__ counts,
                            int E, int Etot) {
  int e = blockIdx.x * blockDim.x + threadIdx.x;
  if (e >= Etot) return;
  int d = (e < E) ? dst[e] : (e - E);
  atomicAdd(&counts[d], 1);
}

__global__ __launch_bounds__(1024) void scan_kernel(const int* __restrict__ counts,
                                                    int* __restrict__ offsets, int n) {
  __shared__ int sh_carry;
  __shared__ int wsum[16];
  const int t = threadIdx.x, lane = t & 63, w = t >> 6;
  if (t == 0) sh_carry = 0;
  __syncthreads();
  for (int base = 0; base < n; base += 4096) {
    int i = base + t * 4;
    int c0 = 0, c1 = 0, c2 = 0, c3 = 0;
    if (i + 3 < n) {
      int4 v = *(const int4*)&counts[i];
      c0 = v.x; c1 = v.y; c2 = v.z; c3 = v.w;
    } else {
      if (i < n) c0 = counts[i];
      if (i + 1 < n) c1 = counts[i + 1];
      if (i + 2 < n) c2 = counts[i + 2];
    }
    int ts = c0 + c1 + c2 + c3;
    int x = ts;
#pragma unroll
    for (int off2 = 1; off2 < 64; off2 <<= 1) {
      int y = __shfl_up(x, off2, 64);
      if (lane >= off2) x += y;
    }
    if (lane == 63) wsum[w] = x;
    int carry = sh_carry;
    __syncthreads();
    int prefix = carry;
    for (int ww = 0; ww < w; ++ww) prefix += wsum[ww];
    int e0 = prefix + x - ts;  // exclusive prefix at element i
    if (i + 3 < n) {
      int4 o;
      o.x = e0; o.y = e0 + c0; o.z = e0 + c0 + c1; o.w = e0 + c0 + c1 + c2;
      *(int4*)&offsets[i] = o;
    } else {
      if (i < n) offsets[i] = e0;
      if (i + 1 < n) offsets[i + 1] = e0 + c0;
      if (i + 2 < n) offsets[i + 2] = e0 + c0 + c1;
    }
    __syncthreads();
    if (t == 1023) sh_carry = prefix + x;
    __syncthreads();
  }
  if (threadIdx.x == 0) offsets[n] = sh_carry;
}

__global__ void scatter_kernel(const int* __restrict__ src, const int* __restrict__ dst,
    const int* __restrict__ offsets, int* __restrict__ cursor,
    int* __restrict__ src_sorted, int E, int Etot) {
  int e = blockIdx.x * blockDim.x + threadIdx.x;
  if (e >= Etot) return;
  int s = (e < E) ? src[e] : (e - E);
  int d = (e < E) ? dst[e] : (e - E);
  int pos = offsets[d] + atomicAdd(&cursor[d], 1);
  src_sorted[pos] = s;
}

// ---------------- per-edge segment max ----------------
__global__ void edge_max1_kernel(const int* __restrict__ src, const int* __restrict__ dst,
    const float* __restrict__ as1, const float* __restrict__ ad1,
    unsigned* __restrict__ m1, int E, int Etot) {
  int e = blockIdx.x * blockDim.x + threadIdx.x;
  if (e >= Etot) return;
  int s = (e < E) ? src[e] : (e - E);
  int d = (e < E) ? dst[e] : (e - E);
#pragma unroll
  for (int hh = 0; hh < 4; ++hh) {
    float l = lrelu(as1[s * 4 + hh] + ad1[d * 4 + hh]);
    atomicMax(&m1[d * 4 + hh], fenc(l));
  }
}

__global__ void edge_max2_kernel(const int* __restrict__ src, const int* __restrict__ dst,
    const float* __restrict__ as2, const float* __restrict__ ad2,
    unsigned* __restrict__ m2, int E, int Etot) {
  int e = blockIdx.x * blockDim.x + threadIdx.x;
  if (e >= Etot) return;
  int s = (e < E) ? src[e] : (e - E);
  int d = (e < E) ? dst[e] : (e - E);
  float l = lrelu(as2[s] + ad2[d]);
  atomicMax(&m2[d], fenc(l));
}

// ---------------- aggregation (wave per dst node) ----------------
__global__ __launch_bounds__(256) void agg1_kernel(const float* __restrict__ h1,
    const float* __restrict__ as1, const float* __restrict__ ad1,
    const unsigned* __restrict__ m1, const int* __restrict__ offsets,
    const int* __restrict__ src_sorted, const float* __restrict__ b1,
    float* __restrict__ out1, int N) {
  int wid = (blockIdx.x << 2) + (threadIdx.x >> 6);
  int lane = threadIdx.x & 63;
  if (wid >= N) return;
  float md0 = fdec(m1[wid * 4 + 0]), md1 = fdec(m1[wid * 4 + 1]);
  float md2 = fdec(m1[wid * 4 + 2]), md3 = fdec(m1[wid * 4 + 3]);
  float ah0 = ad1[wid * 4 + 0], ah1 = ad1[wid * 4 + 1];
  float ah2 = ad1[wid * 4 + 2], ah3 = ad1[wid * 4 + 3];
  float acc0 = 0.f, acc1 = 0.f, acc2 = 0.f, acc3 = 0.f;
  float ds0 = 0.f, ds1 = 0.f, ds2 = 0.f, ds3 = 0.f;
  int st = offsets[wid], en = offsets[wid + 1];
  for (int i = st; i < en; ++i) {
    int s = src_sorted[i];
    float4 a4 = *(const float4*)&as1[(size_t)s * 4];
    const float* hr = h1 + (size_t)s * 256;
    float p0 = __expf(lrelu(a4.x + ah0) - md0);
    float p1 = __expf(lrelu(a4.y + ah1) - md1);
    float p2 = __expf(lrelu(a4.z + ah2) - md2);
    float p3 = __expf(lrelu(a4.w + ah3) - md3);
    ds0 += p0; ds1 += p1; ds2 += p2; ds3 += p3;
    acc0 += p0 * hr[lane];
    acc1 += p1 * hr[64 + lane];
    acc2 += p2 * hr[128 + lane];
    acc3 += p3 * hr[192 + lane];
  }
  size_t ob = (size_t)wid * 256;
  out1[ob + lane]       = fmaxf(acc0 / (ds0 + 1e-16f) + b1[lane], 0.f);
  out1[ob + 64 + lane]  = fmaxf(acc1 / (ds1 + 1e-16f) + b1[64 + lane], 0.f);
  out1[ob + 128 + lane] = fmaxf(acc2 / (ds2 + 1e-16f) + b1[128 + lane], 0.f);
  out1[ob + 192 + lane] = fmaxf(acc3 / (ds3 + 1e-16f) + b1[192 + lane], 0.f);
}

__global__ __launch_bounds__(256) void agg2_kernel(const float* __restrict__ h2,
    const float* __restrict__ as2, const float* __restrict__ ad2,
    const unsigned* __restrict__ m2, const int* __restrict__ offsets,
    const int* __restrict__ src_sorted, const float* __restrict__ b2,
    float* __restrict__ out, int N) {
  int wid = (blockIdx.x << 2) + (threadIdx.x >> 6);
  int lane = threadIdx.x & 63;
  if (wid >= N) return;
  float md = fdec(m2[wid]);
  float ah = ad2[wid];
  float acc = 0.f, ds = 0.f;
  int st = offsets[wid], en = offsets[wid + 1];
  for (int i = st; i < en; ++i) {
    int s = src_sorted[i];
    float p = __expf(lrelu(as2[s] + ah) - md);
    ds += p;
    acc += p * h2[(size_t)s * 64 + lane];
  }
  out[(size_t)wid * 64 + lane] = acc / (ds + 1e-16f) + b2[lane];
}

// ---------------- launch ----------------
extern "C" void kernel_launch(void* const* d_in, const int* in_sizes, int n_in,
                              void* d_out, int out_size, void* d_ws, size_t ws_size,
                              hipStream_t stream) {
  const float* x      = (const float*)d_in[0];
  const int*   ei     = (const int*)d_in[1];
  const float* W1     = (const float*)d_in[2];
  const float* a_src1 = (const float*)d_in[3];
  const float* a_dst1 = (const float*)d_in[4];
  const float* b1     = (const float*)d_in[5];
  const float* W2     = (const float*)d_in[6];
  const float* a_src2 = (const float*)d_in[7];
  const float* a_dst2 = (const float*)d_in[8];
  const float* b2     = (const float*)d_in[9];
  float* out = (float*)d_out;

  const int IN = 256, HD = 256, D2 = 64;  // layer1 in/out widths, layer2 out width
  const int N = in_sizes[0] / IN;
  const int E = in_sizes[1] / 2;
  const int Etot = E + N;
  const int* srcp = ei;
  const int* dstp = ei + E;

  // workspace carve (256B-aligned bump allocator)
  uintptr_t base = (uintptr_t)d_ws;
  auto alloc_bytes = [&](size_t nbytes) -> void* {
    void* p = (void*)base;
    base += (nbytes + 255) & ~(size_t)255;
    return p;
  };
  float* h1        = (float*)alloc_bytes((size_t)N * HD * 4);
  float* out1      = (float*)alloc_bytes((size_t)N * HD * 4);
  float* h2        = (float*)alloc_bytes((size_t)N * D2 * 4);
  float* as1       = (float*)alloc_bytes((size_t)N * 4 * 4);
  float* ad1       = (float*)alloc_bytes((size_t)N * 4 * 4);
  float* as2       = (float*)alloc_bytes((size_t)N * 4);
  float* ad2       = (float*)alloc_bytes((size_t)N * 4);
  // zero-init region start
  unsigned* m1     = (unsigned*)alloc_bytes((size_t)N * 4 * 4);
  unsigned* m2     = (unsigned*)alloc_bytes((size_t)N * 4);
  int* counts      = (int*)alloc_bytes((size_t)(N + 1) * 4);
  int* cursor      = (int*)alloc_bytes((size_t)N * 4);
  uintptr_t zero_end = base;
  // zero-init region end
  int* offsets     = (int*)alloc_bytes((size_t)(N + 1) * 4);
  int* src_sorted  = (int*)alloc_bytes((size_t)Etot * 4);

  hipMemsetAsync((void*)m1, 0, zero_end - (uintptr_t)m1, stream);

  const int nwb = (N + 3) / 4;            // wave-per-node blocks (4 waves/block)
  const int neb = (Etot + 255) / 256;     // edge blocks

  // layer 1
  gemm_f32<<<dim3(HD / BN, (N + BM - 1) / BM), 256, 0, stream>>>(x, W1, h1, N, HD, IN);
  alpha1_kernel<<<nwb, 256, 0, stream>>>(h1, a_src1, a_dst1, as1, ad1, N);
  // CSR (shared by both layers)
  hist_kernel<<<neb, 256, 0, stream>>>(dstp, counts, E, Etot);
  scan_kernel<<<1, 1024, 0, stream>>>(counts, offsets, N);
  scatter_kernel<<<neb, 256, 0, stream>>>(srcp, dstp, offsets, cursor, src_sorted, E, Etot);
  edge_max1_kernel<<<neb, 256, 0, stream>>>(srcp, dstp, as1, ad1, m1, E, Etot);
  agg1_kernel<<<nwb, 256, 0, stream>>>(h1, as1, ad1, m1, offsets, src_sorted, b1, out1, N);
  // layer 2
  gemm_f32<<<dim3(D2 / BN, (N + BM - 1) / BM), 256, 0, stream>>>(out1, W2, h2, N, D2, HD);
  alpha2_kernel<<<nwb, 256, 0, stream>>>(h2, a_src2, a_dst2, as2, ad2, N);
  edge_max2_kernel<<<neb, 256, 0, stream>>>(srcp, dstp, as2, ad2, m2, E, Etot);
  agg2_kernel<<<nwb, 256, 0, stream>>>(h2, as2, ad2, m2, offsets, src_sorted, b2, out, N);
}

// Round 2
// 627.822 us; speedup vs baseline: 1.0670x; 1.0670x over previous
//
#include <hip/hip_runtime.h>
#include <hip/hip_bf16.h>

typedef __attribute__((ext_vector_type(8))) short short8v;
typedef __attribute__((ext_vector_type(4))) float f32x4;

// ---------------- helpers ----------------
__device__ __forceinline__ unsigned fenc(float f) {
  unsigned u = __float_as_uint(f);
  return (u & 0x80000000u) ? ~u : (u | 0x80000000u);
}
__device__ __forceinline__ float fdec(unsigned e) {
  return (e & 0x80000000u) ? __uint_as_float(e & 0x7fffffffu) : __uint_as_float(~e);
}
__device__ __forceinline__ float lrelu(float x) { return x > 0.f ? x : 0.2f * x; }
__device__ __forceinline__ ushort f2bf(float v) {
  __hip_bfloat16 b = __float2bfloat16(v);
  return *(ushort*)&b;
}
__device__ __forceinline__ float bf2f(ushort u) {
  return __uint_as_float(((unsigned)u) << 16);
}
__device__ __forceinline__ void gload16(const ushort* g, ushort* l) {
  __builtin_amdgcn_global_load_lds((const __attribute__((address_space(1))) void*)g,
                                   (__attribute__((address_space(3))) void*)l, 16, 0, 0);
}

// ---------------- pack kernels (f32 -> bf16 hi/lo split) ----------------
// A layout: [Mpad][512] bf16, cols [0,256)=hi(x), [256,512)=lo(x). The GEMM
// folds k>=512 back onto [0,256) (hi again), giving K'=768 = hi|lo|hi.
__global__ __launch_bounds__(256) void pack_x_kernel(const float* __restrict__ x,
    ushort* __restrict__ A, int N, int Mpad) {
  int idx = blockIdx.x * 256 + threadIdx.x;
  if (idx >= Mpad * 256) return;
  int row = idx >> 8, c = idx & 255;
  float v = (row < N) ? x[idx] : 0.f;
  ushort hi = f2bf(v);
  ushort lo = f2bf(v - bf2f(hi));
  A[(size_t)row * 512 + c] = hi;
  A[(size_t)row * 512 + 256 + c] = lo;
}

// Bt layout: [NN][768] bf16, per col: k in [0,256)=hi(W), [256,512)=hi(W),
// [512,768)=lo(W).  (pairs with A' = hi|lo|hi -> hi*hi + lo*hi + hi*lo)
__global__ __launch_bounds__(256) void pack_w_kernel(const float* __restrict__ W,
    ushort* __restrict__ Bt, int NN) {
  int idx = blockIdx.x * 256 + threadIdx.x;  // over 256*NN, W is [256][NN]
  if (idx >= 256 * NN) return;
  int k = idx / NN, col = idx % NN;
  float v = W[idx];
  ushort hi = f2bf(v), lo = f2bf(v - bf2f(hi));
  size_t b = (size_t)col * 768;
  Bt[b + k] = hi;
  Bt[b + 256 + k] = hi;
  Bt[b + 512 + k] = lo;
}

// ---------------- MFMA GEMM with fused bf16-output + attention dots ----------
// A: [Mpad][512] bf16 (k-folded), Bt: [NN][768] bf16 (B transposed).
// Hb: [M][NN] bf16 output copy. os/od: [M][NN/64] attention dots.
template<int BN, int NF>
__global__ __launch_bounds__(256) void gemm_mfma(
    const ushort* __restrict__ A, const ushort* __restrict__ Bt,
    const float* __restrict__ avs, const float* __restrict__ avd,
    ushort* __restrict__ Hb, float* __restrict__ os, float* __restrict__ od,
    int M, int NN) {
  constexpr int BM = 128, BK = 64, K = 768, KA = 512;
  __shared__ ushort As[BM * BK];
  __shared__ ushort Bs[BN * BK];
  const int t = threadIdx.x, l = t & 63, w = t >> 6;
  const int l15 = l & 15, l4 = l >> 4;
  const int m0 = blockIdx.y * BM, n0 = blockIdx.x * BN;
  const int wr = w >> 1, wc = w & 1;
  f32x4 acc[4][NF];
#pragma unroll
  for (int m = 0; m < 4; ++m)
#pragma unroll
    for (int n = 0; n < NF; ++n) acc[m][n] = (f32x4){0.f, 0.f, 0.f, 0.f};

  for (int kk = 0; kk < K; kk += BK) {
    const int ka = (kk < KA) ? kk : kk - KA;
    __syncthreads();
#pragma unroll
    for (int i = 0; i < 4; ++i) {  // A tile: 16 wave-chunks of 1KB
      int q = w * 4 + i;
      int c = q * 64 + l;
      int row = c >> 3, k8 = c & 7;
      int k8s = k8 ^ (row & 7);  // pre-swizzled source so LDS reads are conflict-free
      gload16(&A[(size_t)(m0 + row) * KA + ka + k8s * 8], &As[q * 512]);
    }
    constexpr int BCHW = (BN * 8 / 64) / 4;
#pragma unroll
    for (int i = 0; i < BCHW; ++i) {
      int q = w * BCHW + i;
      int c = q * 64 + l;
      int col = c >> 3, k8 = c & 7;
      int k8s = k8 ^ (col & 7);
      gload16(&Bt[(size_t)(n0 + col) * K + kk + k8s * 8], &Bs[q * 512]);
    }
    __syncthreads();
#pragma unroll
    for (int ks = 0; ks < 2; ++ks) {
      int kb = ks * 4 + l4;
      short8v af[4], bfr[NF];
#pragma unroll
      for (int m = 0; m < 4; ++m) {
        int row = wr * 64 + m * 16 + l15;
        af[m] = *(const short8v*)&As[row * 64 + (kb ^ (row & 7)) * 8];
      }
#pragma unroll
      for (int n = 0; n < NF; ++n) {
        int col = wc * (NF * 16) + n * 16 + l15;
        bfr[n] = *(const short8v*)&Bs[col * 64 + (kb ^ (col & 7)) * 8];
      }
#pragma unroll
      for (int m = 0; m < 4; ++m)
#pragma unroll
        for (int n = 0; n < NF; ++n)
          acc[m][n] = __builtin_amdgcn_mfma_f32_16x16x32_bf16(af[m], bfr[n], acc[m][n], 0, 0, 0);
    }
  }
  // ---- epilogue: bf16 output copy ----
#pragma unroll
  for (int m = 0; m < 4; ++m) {
    int rbase = m0 + wr * 64 + m * 16 + l4 * 4;
#pragma unroll
    for (int n = 0; n < NF; ++n) {
      int col = n0 + wc * (NF * 16) + n * 16 + l15;
#pragma unroll
      for (int r = 0; r < 4; ++r) {
        int row = rbase + r;
        if (row < M) Hb[(size_t)row * NN + col] = f2bf(acc[m][n][r]);
      }
    }
  }
  // ---- epilogue: attention dots (per-row, reduce over the 16-lane group) ----
  float cs[NF], cd[NF];
#pragma unroll
  for (int n = 0; n < NF; ++n) {
    int gc = n0 + wc * (NF * 16) + n * 16 + l15;
    cs[n] = avs[gc];
    cd[n] = avd[gc];
  }
  const int H = NN >> 6;
  const int head = (n0 + wc * (NF * 16)) >> 6;
#pragma unroll
  for (int m = 0; m < 4; ++m) {
#pragma unroll
    for (int r = 0; r < 4; ++r) {
      float ps = 0.f, pd = 0.f;
#pragma unroll
      for (int n = 0; n < NF; ++n) { ps += acc[m][n][r] * cs[n]; pd += acc[m][n][r] * cd[n]; }
#pragma unroll
      for (int off = 1; off < 16; off <<= 1) {
        ps += __shfl_xor(ps, off, 64);
        pd += __shfl_xor(pd, off, 64);
      }
      if (l15 == 0) {
        int row = m0 + wr * 64 + m * 16 + l4 * 4 + r;
        if (row < M) {
          if (NF == 4) {  // wave covers the full 64-wide head: exclusive owner
            os[(size_t)row * H + head] = ps;
            od[(size_t)row * H + head] = pd;
          } else {        // two waves split the head
            atomicAdd(&os[row], ps);
            atomicAdd(&od[row], pd);
          }
        }
      }
    }
  }
}

// ---------------- CSR build ----------------
__global__ void hist_kernel(const int* __restrict__ dst, int* __restrict__ counts,
                            int E, int Etot) {
  int e = blockIdx.x * blockDim.x + threadIdx.x;
  if (e >= Etot) return;
  int d = (e < E) ? dst[e] : (e - E);
  atomicAdd(&counts[d], 1);
}

__global__ __launch_bounds__(1024) void scan_kernel(const int* __restrict__ counts,
                                                    int* __restrict__ offsets, int n) {
  __shared__ int wsums[16];
  int t = threadIdx.x, lane = t & 63, w = t >> 6;
  int per = (n + 1023) >> 10;
  int s0 = t * per;
  int s1 = min(s0 + per, n);
  int s = 0;
  for (int i = s0; i < s1; ++i) s += counts[i];
  int x = s;
#pragma unroll
  for (int off = 1; off < 64; off <<= 1) {
    int y = __shfl_up(x, off, 64);
    if (lane >= off) x += y;
  }
  if (lane == 63) wsums[w] = x;
  __syncthreads();
  int wpre = 0;
  for (int i = 0; i < w; ++i) wpre += wsums[i];
  int run = wpre + x - s;  // exclusive prefix
  for (int i = s0; i < s1; ++i) { offsets[i] = run; run += counts[i]; }
  if (t == 1023) offsets[n] = run;
}

__global__ void scatter_kernel(const int* __restrict__ src, const int* __restrict__ dst,
    const int* __restrict__ offsets, int* __restrict__ cursor,
    int* __restrict__ src_sorted, int E, int Etot) {
  int e = blockIdx.x * blockDim.x + threadIdx.x;
  if (e >= Etot) return;
  int s = (e < E) ? src[e] : (e - E);
  int d = (e < E) ? dst[e] : (e - E);
  int pos = offsets[d] + atomicAdd(&cursor[d], 1);
  src_sorted[pos] = s;
}

// ---------------- per-edge segment max ----------------
__global__ void edge_max1_kernel(const int* __restrict__ src, const int* __restrict__ dst,
    const float* __restrict__ as1, const float* __restrict__ ad1,
    unsigned* __restrict__ m1, int E, int Etot) {
  int e = blockIdx.x * blockDim.x + threadIdx.x;
  if (e >= Etot) return;
  int s = (e < E) ? src[e] : (e - E);
  int d = (e < E) ? dst[e] : (e - E);
#pragma unroll
  for (int hh = 0; hh < 4; ++hh) {
    float l = lrelu(as1[s * 4 + hh] + ad1[d * 4 + hh]);
    atomicMax(&m1[d * 4 + hh], fenc(l));
  }
}

__global__ void edge_max2_kernel(const int* __restrict__ src, const int* __restrict__ dst,
    const float* __restrict__ as2, const float* __restrict__ ad2,
    unsigned* __restrict__ m2, int E, int Etot) {
  int e = blockIdx.x * blockDim.x + threadIdx.x;
  if (e >= Etot) return;
  int s = (e < E) ? src[e] : (e - E);
  int d = (e < E) ? dst[e] : (e - E);
  float l = lrelu(as2[s] + ad2[d]);
  atomicMax(&m2[d], fenc(l));
}

// ---------------- aggregation layer 1 (bf16 gather, packs gemm2 input) -------
__global__ __launch_bounds__(256) void agg1_kernel(const ushort* __restrict__ h1b,
    const float* __restrict__ as1, const float* __restrict__ ad1,
    const unsigned* __restrict__ m1, const int* __restrict__ offsets,
    const int* __restrict__ src_sorted, const float* __restrict__ b1,
    ushort* __restrict__ A2, int N, int Mpad) {
  int wid = (blockIdx.x << 2) + (threadIdx.x >> 6);
  int lane = threadIdx.x & 63;
  if (wid >= Mpad) return;
  size_t ab = (size_t)wid * 512;
  if (wid >= N) {  // zero-fill pad rows for gemm2
#pragma unroll
    for (int i = 0; i < 8; ++i) A2[ab + i * 64 + lane] = 0;
    return;
  }
  float md0 = fdec(m1[wid * 4 + 0]), md1 = fdec(m1[wid * 4 + 1]);
  float md2 = fdec(m1[wid * 4 + 2]), md3 = fdec(m1[wid * 4 + 3]);
  float ah0 = ad1[wid * 4 + 0], ah1 = ad1[wid * 4 + 1];
  float ah2 = ad1[wid * 4 + 2], ah3 = ad1[wid * 4 + 3];
  float acc0 = 0.f, acc1 = 0.f, acc2 = 0.f, acc3 = 0.f;
  float ds0 = 0.f, ds1 = 0.f, ds2 = 0.f, ds3 = 0.f;
  int st = offsets[wid], en = offsets[wid + 1];
  for (int i = st; i < en; ++i) {
    int s = src_sorted[i];
    float4 a4 = *(const float4*)&as1[(size_t)s * 4];
    const ushort* hr = h1b + (size_t)s * 256;
    float p0 = __expf(lrelu(a4.x + ah0) - md0);
    float p1 = __expf(lrelu(a4.y + ah1) - md1);
    float p2 = __expf(lrelu(a4.z + ah2) - md2);
    float p3 = __expf(lrelu(a4.w + ah3) - md3);
    ds0 += p0; ds1 += p1; ds2 += p2; ds3 += p3;
    acc0 += p0 * bf2f(hr[lane]);
    acc1 += p1 * bf2f(hr[64 + lane]);
    acc2 += p2 * bf2f(hr[128 + lane]);
    acc3 += p3 * bf2f(hr[192 + lane]);
  }
  float v[4];
  v[0] = fmaxf(acc0 / (ds0 + 1e-16f) + b1[lane], 0.f);
  v[1] = fmaxf(acc1 / (ds1 + 1e-16f) + b1[64 + lane], 0.f);
  v[2] = fmaxf(acc2 / (ds2 + 1e-16f) + b1[128 + lane], 0.f);
  v[3] = fmaxf(acc3 / (ds3 + 1e-16f) + b1[192 + lane], 0.f);
#pragma unroll
  for (int h = 0; h < 4; ++h) {
    ushort hi = f2bf(v[h]);
    ushort lo = f2bf(v[h] - bf2f(hi));
    A2[ab + h * 64 + lane] = hi;
    A2[ab + 256 + h * 64 + lane] = lo;
  }
}

// ---------------- aggregation layer 2 (bf16 gather, writes final out) --------
__global__ __launch_bounds__(256) void agg2_kernel(const ushort* __restrict__ h2b,
    const float* __restrict__ as2, const float* __restrict__ ad2,
    const unsigned* __restrict__ m2, const int* __restrict__ offsets,
    const int* __restrict__ src_sorted, const float* __restrict__ b2,
    float* __restrict__ out, int N) {
  int wid = (blockIdx.x << 2) + (threadIdx.x >> 6);
  int lane = threadIdx.x & 63;
  if (wid >= N) return;
  float md = fdec(m2[wid]);
  float ah = ad2[wid];
  float acc = 0.f, ds = 0.f;
  int st = offsets[wid], en = offsets[wid + 1];
  for (int i = st; i < en; ++i) {
    int s = src_sorted[i];
    float p = __expf(lrelu(as2[s] + ah) - md);
    ds += p;
    acc += p * bf2f(h2b[(size_t)s * 64 + lane]);
  }
  out[(size_t)wid * 64 + lane] = acc / (ds + 1e-16f) + b2[lane];
}

// ---------------- launch ----------------
extern "C" void kernel_launch(void* const* d_in, const int* in_sizes, int n_in,
                              void* d_out, int out_size, void* d_ws, size_t ws_size,
                              hipStream_t stream) {
  const float* x      = (const float*)d_in[0];
  const int*   ei     = (const int*)d_in[1];
  const float* W1     = (const float*)d_in[2];
  const float* a_src1 = (const float*)d_in[3];
  const float* a_dst1 = (const float*)d_in[4];
  const float* b1     = (const float*)d_in[5];
  const float* W2     = (const float*)d_in[6];
  const float* a_src2 = (const float*)d_in[7];
  const float* a_dst2 = (const float*)d_in[8];
  const float* b2     = (const float*)d_in[9];
  float* out = (float*)d_out;

  const int IN = 256, HD = 256, D2 = 64;
  const int N = in_sizes[0] / IN;
  const int E = in_sizes[1] / 2;
  const int Etot = E + N;
  const int Mpad = ((N + 127) / 128) * 128;
  const int* srcp = ei;
  const int* dstp = ei + E;

  uintptr_t base = (uintptr_t)d_ws;
  auto alloc_bytes = [&](size_t nbytes) -> void* {
    void* p = (void*)base;
    base += (nbytes + 255) & ~(size_t)255;
    return p;
  };
  ushort* A1       = (ushort*)alloc_bytes((size_t)Mpad * 512 * 2);
  ushort* A2       = (ushort*)alloc_bytes((size_t)Mpad * 512 * 2);
  ushort* h1b      = (ushort*)alloc_bytes((size_t)N * HD * 2);
  ushort* h2b      = (ushort*)alloc_bytes((size_t)N * D2 * 2);
  ushort* B1t      = (ushort*)alloc_bytes((size_t)HD * 768 * 2);
  ushort* B2t      = (ushort*)alloc_bytes((size_t)D2 * 768 * 2);
  // zero-init region start
  float* as1       = (float*)alloc_bytes((size_t)N * 4 * 4);
  float* ad1       = (float*)alloc_bytes((size_t)N * 4 * 4);
  float* as2       = (float*)alloc_bytes((size_t)N * 4);
  float* ad2       = (float*)alloc_bytes((size_t)N * 4);
  unsigned* m1     = (unsigned*)alloc_bytes((size_t)N * 4 * 4);
  unsigned* m2     = (unsigned*)alloc_bytes((size_t)N * 4);
  int* counts      = (int*)alloc_bytes((size_t)(N + 1) * 4);
  int* cursor      = (int*)alloc_bytes((size_t)N * 4);
  uintptr_t zero_end = base;
  // zero-init region end
  int* offsets     = (int*)alloc_bytes((size_t)(N + 1) * 4);
  int* src_sorted  = (int*)alloc_bytes((size_t)Etot * 4);

  hipMemsetAsync((void*)as1, 0, zero_end - (uintptr_t)as1, stream);

  const int nwb  = (N + 3) / 4;
  const int nwbp = (Mpad + 3) / 4;
  const int neb  = (Etot + 255) / 256;

  // packing
  pack_x_kernel<<<(Mpad * 256 + 255) / 256, 256, 0, stream>>>(x, A1, N, Mpad);
  pack_w_kernel<<<(256 * HD + 255) / 256, 256, 0, stream>>>(W1, B1t, HD);
  pack_w_kernel<<<(256 * D2 + 255) / 256, 256, 0, stream>>>(W2, B2t, D2);
  // CSR (independent of layer 1)
  hist_kernel<<<neb, 256, 0, stream>>>(dstp, counts, E, Etot);
  scan_kernel<<<1, 1024, 0, stream>>>(counts, offsets, N);
  scatter_kernel<<<neb, 256, 0, stream>>>(srcp, dstp, offsets, cursor, src_sorted, E, Etot);
  // layer 1
  gemm_mfma<128, 4><<<dim3(HD / 128, Mpad / 128), 256, 0, stream>>>(
      A1, B1t, a_src1, a_dst1, h1b, as1, ad1, N, HD);
  edge_max1_kernel<<<neb, 256, 0, stream>>>(srcp, dstp, as1, ad1, m1, E, Etot);
  agg1_kernel<<<nwbp, 256, 0, stream>>>(h1b, as1, ad1, m1, offsets, src_sorted, b1, A2, N, Mpad);
  // layer 2
  gemm_mfma<64, 2><<<dim3(D2 / 64, Mpad / 128), 256, 0, stream>>>(
      A2, B2t, a_src2, a_dst2, h2b, as2, ad2, N, D2);
  edge_max2_kernel<<<neb, 256, 0, stream>>>(srcp, dstp, as2, ad2, m2, E, Etot);
  agg2_kernel<<<nwb, 256, 0, stream>>>(h2b, as2, ad2, m2, offsets, src_sorted, b2, out, N);
}

// Round 3
// 465.768 us; speedup vs baseline: 1.4383x; 1.3479x over previous
//
#include <hip/hip_runtime.h>
#include <hip/hip_bf16.h>

typedef __attribute__((ext_vector_type(8))) short short8v;
typedef __attribute__((ext_vector_type(4))) float f32x4;

// ---------------- helpers ----------------
__device__ __forceinline__ float lrelu(float x) { return x > 0.f ? x : 0.2f * x; }
__device__ __forceinline__ ushort f2bf(float v) {
  __hip_bfloat16 b = __float2bfloat16(v);
  return *(ushort*)&b;
}
__device__ __forceinline__ float bf2f(ushort u) {
  return __uint_as_float(((unsigned)u) << 16);
}
__device__ __forceinline__ void gload16(const ushort* g, ushort* l) {
  __builtin_amdgcn_global_load_lds((const __attribute__((address_space(1))) void*)g,
                                   (__attribute__((address_space(3))) void*)l, 16, 0, 0);
}

// ---------------- pack kernels (f32 -> bf16 hi/lo split) ----------------
// A layout: [Mpad][512] bf16, cols [0,256)=hi(x), [256,512)=lo(x). The GEMM
// folds k>=512 back onto [0,256) (hi again), giving K'=768 = hi|lo|hi.
__global__ __launch_bounds__(256) void pack_x_kernel(const float* __restrict__ x,
    ushort* __restrict__ A, int N, int Mpad) {
  int idx = blockIdx.x * 256 + threadIdx.x;
  if (idx >= Mpad * 256) return;
  int row = idx >> 8, c = idx & 255;
  float v = (row < N) ? x[idx] : 0.f;
  ushort hi = f2bf(v);
  ushort lo = f2bf(v - bf2f(hi));
  A[(size_t)row * 512 + c] = hi;
  A[(size_t)row * 512 + 256 + c] = lo;
}

// Bt layout: [NN][768] bf16, per col: k in [0,256)=hi(W), [256,512)=hi(W),
// [512,768)=lo(W).  (pairs with A' = hi|lo|hi -> hi*hi + lo*hi + hi*lo)
__global__ __launch_bounds__(256) void pack_w_kernel(const float* __restrict__ W,
    ushort* __restrict__ Bt, int NN) {
  int idx = blockIdx.x * 256 + threadIdx.x;  // over 256*NN, W is [256][NN]
  if (idx >= 256 * NN) return;
  int k = idx / NN, col = idx % NN;
  float v = W[idx];
  ushort hi = f2bf(v), lo = f2bf(v - bf2f(hi));
  size_t b = (size_t)col * 768;
  Bt[b + k] = hi;
  Bt[b + 256 + k] = hi;
  Bt[b + 512 + k] = lo;
}

// ---------------- MFMA GEMM with fused bf16-output + attention dots ----------
// A: [Mpad][512] bf16 (k-folded), Bt: [NN][768] bf16 (B transposed).
// Hb: [M][NN] bf16 output copy. os/od: [M][NN/64] attention dots.
template<int BN, int NF>
__global__ __launch_bounds__(256) void gemm_mfma(
    const ushort* __restrict__ A, const ushort* __restrict__ Bt,
    const float* __restrict__ avs, const float* __restrict__ avd,
    ushort* __restrict__ Hb, float* __restrict__ os, float* __restrict__ od,
    int M, int NN) {
  constexpr int BM = 128, BK = 64, K = 768, KA = 512;
  __shared__ ushort As[BM * BK];
  __shared__ ushort Bs[BN * BK];
  const int t = threadIdx.x, l = t & 63, w = t >> 6;
  const int l15 = l & 15, l4 = l >> 4;
  const int m0 = blockIdx.y * BM, n0 = blockIdx.x * BN;
  const int wr = w >> 1, wc = w & 1;
  f32x4 acc[4][NF];
#pragma unroll
  for (int m = 0; m < 4; ++m)
#pragma unroll
    for (int n = 0; n < NF; ++n) acc[m][n] = (f32x4){0.f, 0.f, 0.f, 0.f};

  for (int kk = 0; kk < K; kk += BK) {
    const int ka = (kk < KA) ? kk : kk - KA;
    __syncthreads();
#pragma unroll
    for (int i = 0; i < 4; ++i) {  // A tile: 16 wave-chunks of 1KB
      int q = w * 4 + i;
      int c = q * 64 + l;
      int row = c >> 3, k8 = c & 7;
      int k8s = k8 ^ (row & 7);  // pre-swizzled source so LDS reads are conflict-free
      gload16(&A[(size_t)(m0 + row) * KA + ka + k8s * 8], &As[q * 512]);
    }
    constexpr int BCHW = (BN * 8 / 64) / 4;
#pragma unroll
    for (int i = 0; i < BCHW; ++i) {
      int q = w * BCHW + i;
      int c = q * 64 + l;
      int col = c >> 3, k8 = c & 7;
      int k8s = k8 ^ (col & 7);
      gload16(&Bt[(size_t)(n0 + col) * K + kk + k8s * 8], &Bs[q * 512]);
    }
    __syncthreads();
#pragma unroll
    for (int ks = 0; ks < 2; ++ks) {
      int kb = ks * 4 + l4;
      short8v af[4], bfr[NF];
#pragma unroll
      for (int m = 0; m < 4; ++m) {
        int row = wr * 64 + m * 16 + l15;
        af[m] = *(const short8v*)&As[row * 64 + (kb ^ (row & 7)) * 8];
      }
#pragma unroll
      for (int n = 0; n < NF; ++n) {
        int col = wc * (NF * 16) + n * 16 + l15;
        bfr[n] = *(const short8v*)&Bs[col * 64 + (kb ^ (col & 7)) * 8];
      }
#pragma unroll
      for (int m = 0; m < 4; ++m)
#pragma unroll
        for (int n = 0; n < NF; ++n)
          acc[m][n] = __builtin_amdgcn_mfma_f32_16x16x32_bf16(af[m], bfr[n], acc[m][n], 0, 0, 0);
    }
  }
  // ---- epilogue: bf16 output copy ----
#pragma unroll
  for (int m = 0; m < 4; ++m) {
    int rbase = m0 + wr * 64 + m * 16 + l4 * 4;
#pragma unroll
    for (int n = 0; n < NF; ++n) {
      int col = n0 + wc * (NF * 16) + n * 16 + l15;
#pragma unroll
      for (int r = 0; r < 4; ++r) {
        int row = rbase + r;
        if (row < M) Hb[(size_t)row * NN + col] = f2bf(acc[m][n][r]);
      }
    }
  }
  // ---- epilogue: attention dots (per-row, reduce over the 16-lane group) ----
  float cs[NF], cd[NF];
#pragma unroll
  for (int n = 0; n < NF; ++n) {
    int gc = n0 + wc * (NF * 16) + n * 16 + l15;
    cs[n] = avs[gc];
    cd[n] = avd[gc];
  }
  const int H = NN >> 6;
  const int head = (n0 + wc * (NF * 16)) >> 6;
#pragma unroll
  for (int m = 0; m < 4; ++m) {
#pragma unroll
    for (int r = 0; r < 4; ++r) {
      float ps = 0.f, pd = 0.f;
#pragma unroll
      for (int n = 0; n < NF; ++n) { ps += acc[m][n][r] * cs[n]; pd += acc[m][n][r] * cd[n]; }
#pragma unroll
      for (int off = 1; off < 16; off <<= 1) {
        ps += __shfl_xor(ps, off, 64);
        pd += __shfl_xor(pd, off, 64);
      }
      if (l15 == 0) {
        int row = m0 + wr * 64 + m * 16 + l4 * 4 + r;
        if (row < M) {
          if (NF == 4) {  // wave covers the full 64-wide head: exclusive owner
            os[(size_t)row * H + head] = ps;
            od[(size_t)row * H + head] = pd;
          } else {        // two waves split the head
            atomicAdd(&os[row], ps);
            atomicAdd(&od[row], pd);
          }
        }
      }
    }
  }
}

// ---------------- CSR build ----------------
__global__ void hist_kernel(const int* __restrict__ dst, int* __restrict__ counts,
                            int E, int Etot) {
  int e = blockIdx.x * blockDim.x + threadIdx.x;
  if (e >= Etot) return;
  int d = (e < E) ? dst[e] : (e - E);
  atomicAdd(&counts[d], 1);
}

__global__ __launch_bounds__(1024) void scan_kernel(const int* __restrict__ counts,
                                                    int* __restrict__ offsets, int n) {
  __shared__ int wsums[16];
  int t = threadIdx.x, lane = t & 63, w = t >> 6;
  int per = (n + 1023) >> 10;
  int s0 = t * per;
  int s1 = min(s0 + per, n);
  int s = 0;
  for (int i = s0; i < s1; ++i) s += counts[i];
  int x = s;
#pragma unroll
  for (int off = 1; off < 64; off <<= 1) {
    int y = __shfl_up(x, off, 64);
    if (lane >= off) x += y;
  }
  if (lane == 63) wsums[w] = x;
  __syncthreads();
  int wpre = 0;
  for (int i = 0; i < w; ++i) wpre += wsums[i];
  int run = wpre + x - s;  // exclusive prefix
  for (int i = s0; i < s1; ++i) { offsets[i] = run; run += counts[i]; }
  if (t == 1023) offsets[n] = run;
}

__global__ void scatter_kernel(const int* __restrict__ src, const int* __restrict__ dst,
    const int* __restrict__ offsets, int* __restrict__ cursor,
    int* __restrict__ src_sorted, int E, int Etot) {
  int e = blockIdx.x * blockDim.x + threadIdx.x;
  if (e >= Etot) return;
  int s = (e < E) ? src[e] : (e - E);
  int d = (e < E) ? dst[e] : (e - E);
  int pos = offsets[d] + atomicAdd(&cursor[d], 1);
  src_sorted[pos] = s;
}

// ---------------- aggregation layer 1 (in-register segment max; bf16 gather) -
__global__ __launch_bounds__(256) void agg1_kernel(const ushort* __restrict__ h1b,
    const float* __restrict__ as1, const float* __restrict__ ad1,
    const int* __restrict__ offsets, const int* __restrict__ src_sorted,
    const float* __restrict__ b1, ushort* __restrict__ A2, int N, int Mpad) {
  int wid = (blockIdx.x << 2) + (threadIdx.x >> 6);
  int lane = threadIdx.x & 63;
  if (wid >= Mpad) return;
  size_t ab = (size_t)wid * 512;
  if (wid >= N) {  // zero-fill pad rows for gemm2
#pragma unroll
    for (int i = 0; i < 8; ++i) A2[ab + i * 64 + lane] = 0;
    return;
  }
  int st = offsets[wid], en = offsets[wid + 1];
  // pass 1: lane-parallel max of as1 over neighbors (lrelu monotone, ad const
  // per segment => m = lrelu(max(as) + ad))
  float mx0 = -1e30f, mx1 = -1e30f, mx2 = -1e30f, mx3 = -1e30f;
  for (int i = st + lane; i < en; i += 64) {
    int s = src_sorted[i];
    float4 a4 = *(const float4*)&as1[(size_t)s * 4];
    mx0 = fmaxf(mx0, a4.x); mx1 = fmaxf(mx1, a4.y);
    mx2 = fmaxf(mx2, a4.z); mx3 = fmaxf(mx3, a4.w);
  }
#pragma unroll
  for (int off = 32; off > 0; off >>= 1) {
    mx0 = fmaxf(mx0, __shfl_xor(mx0, off, 64));
    mx1 = fmaxf(mx1, __shfl_xor(mx1, off, 64));
    mx2 = fmaxf(mx2, __shfl_xor(mx2, off, 64));
    mx3 = fmaxf(mx3, __shfl_xor(mx3, off, 64));
  }
  float ah0 = ad1[wid * 4 + 0], ah1 = ad1[wid * 4 + 1];
  float ah2 = ad1[wid * 4 + 2], ah3 = ad1[wid * 4 + 3];
  float md0 = lrelu(mx0 + ah0), md1 = lrelu(mx1 + ah1);
  float md2 = lrelu(mx2 + ah2), md3 = lrelu(mx3 + ah3);
  // pass 2: weighted aggregate
  float acc0 = 0.f, acc1 = 0.f, acc2 = 0.f, acc3 = 0.f;
  float ds0 = 0.f, ds1 = 0.f, ds2 = 0.f, ds3 = 0.f;
  for (int i = st; i < en; ++i) {
    int s = src_sorted[i];
    float4 a4 = *(const float4*)&as1[(size_t)s * 4];
    const ushort* hr = h1b + (size_t)s * 256;
    float p0 = __expf(lrelu(a4.x + ah0) - md0);
    float p1 = __expf(lrelu(a4.y + ah1) - md1);
    float p2 = __expf(lrelu(a4.z + ah2) - md2);
    float p3 = __expf(lrelu(a4.w + ah3) - md3);
    ds0 += p0; ds1 += p1; ds2 += p2; ds3 += p3;
    acc0 += p0 * bf2f(hr[lane]);
    acc1 += p1 * bf2f(hr[64 + lane]);
    acc2 += p2 * bf2f(hr[128 + lane]);
    acc3 += p3 * bf2f(hr[192 + lane]);
  }
  float v[4];
  v[0] = fmaxf(acc0 / (ds0 + 1e-16f) + b1[lane], 0.f);
  v[1] = fmaxf(acc1 / (ds1 + 1e-16f) + b1[64 + lane], 0.f);
  v[2] = fmaxf(acc2 / (ds2 + 1e-16f) + b1[128 + lane], 0.f);
  v[3] = fmaxf(acc3 / (ds3 + 1e-16f) + b1[192 + lane], 0.f);
#pragma unroll
  for (int h = 0; h < 4; ++h) {
    ushort hi = f2bf(v[h]);
    ushort lo = f2bf(v[h] - bf2f(hi));
    A2[ab + h * 64 + lane] = hi;
    A2[ab + 256 + h * 64 + lane] = lo;
  }
}

// ---------------- aggregation layer 2 (in-register max; writes final out) ----
__global__ __launch_bounds__(256) void agg2_kernel(const ushort* __restrict__ h2b,
    const float* __restrict__ as2, const float* __restrict__ ad2,
    const int* __restrict__ offsets, const int* __restrict__ src_sorted,
    const float* __restrict__ b2, float* __restrict__ out, int N) {
  int wid = (blockIdx.x << 2) + (threadIdx.x >> 6);
  int lane = threadIdx.x & 63;
  if (wid >= N) return;
  int st = offsets[wid], en = offsets[wid + 1];
  float mx = -1e30f;
  for (int i = st + lane; i < en; i += 64) mx = fmaxf(mx, as2[src_sorted[i]]);
#pragma unroll
  for (int off = 32; off > 0; off >>= 1) mx = fmaxf(mx, __shfl_xor(mx, off, 64));
  float ah = ad2[wid];
  float md = lrelu(mx + ah);
  float acc = 0.f, ds = 0.f;
  for (int i = st; i < en; ++i) {
    int s = src_sorted[i];
    float p = __expf(lrelu(as2[s] + ah) - md);
    ds += p;
    acc += p * bf2f(h2b[(size_t)s * 64 + lane]);
  }
  out[(size_t)wid * 64 + lane] = acc / (ds + 1e-16f) + b2[lane];
}

// ---------------- launch ----------------
extern "C" void kernel_launch(void* const* d_in, const int* in_sizes, int n_in,
                              void* d_out, int out_size, void* d_ws, size_t ws_size,
                              hipStream_t stream) {
  const float* x      = (const float*)d_in[0];
  const int*   ei     = (const int*)d_in[1];
  const float* W1     = (const float*)d_in[2];
  const float* a_src1 = (const float*)d_in[3];
  const float* a_dst1 = (const float*)d_in[4];
  const float* b1     = (const float*)d_in[5];
  const float* W2     = (const float*)d_in[6];
  const float* a_src2 = (const float*)d_in[7];
  const float* a_dst2 = (const float*)d_in[8];
  const float* b2     = (const float*)d_in[9];
  float* out = (float*)d_out;

  const int IN = 256, HD = 256, D2 = 64;
  const int N = in_sizes[0] / IN;
  const int E = in_sizes[1] / 2;
  const int Etot = E + N;
  const int Mpad = ((N + 127) / 128) * 128;
  const int* srcp = ei;
  const int* dstp = ei + E;

  uintptr_t base = (uintptr_t)d_ws;
  auto alloc_bytes = [&](size_t nbytes) -> void* {
    void* p = (void*)base;
    base += (nbytes + 255) & ~(size_t)255;
    return p;
  };
  ushort* A1       = (ushort*)alloc_bytes((size_t)Mpad * 512 * 2);
  ushort* A2       = (ushort*)alloc_bytes((size_t)Mpad * 512 * 2);
  ushort* h1b      = (ushort*)alloc_bytes((size_t)N * HD * 2);
  ushort* h2b      = (ushort*)alloc_bytes((size_t)N * D2 * 2);
  ushort* B1t      = (ushort*)alloc_bytes((size_t)HD * 768 * 2);
  ushort* B2t      = (ushort*)alloc_bytes((size_t)D2 * 768 * 2);
  float* as1       = (float*)alloc_bytes((size_t)N * 4 * 4);
  float* ad1       = (float*)alloc_bytes((size_t)N * 4 * 4);
  // zero-init region start
  float* as2       = (float*)alloc_bytes((size_t)N * 4);
  float* ad2       = (float*)alloc_bytes((size_t)N * 4);
  int* counts      = (int*)alloc_bytes((size_t)(N + 1) * 4);
  int* cursor      = (int*)alloc_bytes((size_t)N * 4);
  uintptr_t zero_end = base;
  // zero-init region end
  int* offsets     = (int*)alloc_bytes((size_t)(N + 1) * 4);
  int* src_sorted  = (int*)alloc_bytes((size_t)Etot * 4);

  hipMemsetAsync((void*)as2, 0, zero_end - (uintptr_t)as2, stream);

  const int nwb  = (N + 3) / 4;
  const int nwbp = (Mpad + 3) / 4;
  const int neb  = (Etot + 255) / 256;

  // packing
  pack_x_kernel<<<(Mpad * 256 + 255) / 256, 256, 0, stream>>>(x, A1, N, Mpad);
  pack_w_kernel<<<(256 * HD + 255) / 256, 256, 0, stream>>>(W1, B1t, HD);
  pack_w_kernel<<<(256 * D2 + 255) / 256, 256, 0, stream>>>(W2, B2t, D2);
  // CSR (independent of layer 1)
  hist_kernel<<<neb, 256, 0, stream>>>(dstp, counts, E, Etot);
  scan_kernel<<<1, 1024, 0, stream>>>(counts, offsets, N);
  scatter_kernel<<<neb, 256, 0, stream>>>(srcp, dstp, offsets, cursor, src_sorted, E, Etot);
  // layer 1
  gemm_mfma<128, 4><<<dim3(HD / 128, Mpad / 128), 256, 0, stream>>>(
      A1, B1t, a_src1, a_dst1, h1b, as1, ad1, N, HD);
  agg1_kernel<<<nwbp, 256, 0, stream>>>(h1b, as1, ad1, offsets, src_sorted, b1, A2, N, Mpad);
  // layer 2
  gemm_mfma<64, 2><<<dim3(D2 / 64, Mpad / 128), 256, 0, stream>>>(
      A2, B2t, a_src2, a_dst2, h2b, as2, ad2, N, D2);
  agg2_kernel<<<nwb, 256, 0, stream>>>(h2b, as2, ad2, offsets, src_sorted, b2, out, N);
}

// Round 4
// 390.499 us; speedup vs baseline: 1.7155x; 1.1928x over previous
//
#include <hip/hip_runtime.h>
#include <hip/hip_bf16.h>

typedef __attribute__((ext_vector_type(8))) short short8v;
typedef __attribute__((ext_vector_type(4))) float f32x4;

// ---------------- helpers ----------------
__device__ __forceinline__ float lrelu(float x) { return x > 0.f ? x : 0.2f * x; }
__device__ __forceinline__ ushort f2bf(float v) {
  __hip_bfloat16 b = __float2bfloat16(v);
  return *(ushort*)&b;
}
__device__ __forceinline__ float bf2f(ushort u) {
  return __uint_as_float(((unsigned)u) << 16);
}
__device__ __forceinline__ void gload16(const ushort* g, ushort* l) {
  __builtin_amdgcn_global_load_lds((const __attribute__((address_space(1))) void*)g,
                                   (__attribute__((address_space(3))) void*)l, 16, 0, 0);
}

// ---------------- pack kernels (f32 -> bf16 hi/lo split) ----------------
__global__ __launch_bounds__(256) void pack_x_kernel(const float* __restrict__ x,
    ushort* __restrict__ A, int N, int Mpad) {
  int idx = blockIdx.x * 256 + threadIdx.x;
  if (idx >= Mpad * 256) return;
  int row = idx >> 8, c = idx & 255;
  float v = (row < N) ? x[idx] : 0.f;
  ushort hi = f2bf(v);
  ushort lo = f2bf(v - bf2f(hi));
  A[(size_t)row * 512 + c] = hi;
  A[(size_t)row * 512 + 256 + c] = lo;
}

__global__ __launch_bounds__(256) void pack_w_kernel(const float* __restrict__ W,
    ushort* __restrict__ Bt, int NN) {
  int idx = blockIdx.x * 256 + threadIdx.x;  // over 256*NN, W is [256][NN]
  if (idx >= 256 * NN) return;
  int k = idx / NN, col = idx % NN;
  float v = W[idx];
  ushort hi = f2bf(v), lo = f2bf(v - bf2f(hi));
  size_t b = (size_t)col * 768;
  Bt[b + k] = hi;
  Bt[b + 256 + k] = hi;
  Bt[b + 512 + k] = lo;
}

// ---------------- MFMA GEMM with fused bf16-output + attention dots ----------
// IL=true: Hb written interleaved as [row][feat*4 + head] (NN=256, 4 heads).
template<int BN, int NF, bool IL>
__global__ __launch_bounds__(256) void gemm_mfma(
    const ushort* __restrict__ A, const ushort* __restrict__ Bt,
    const float* __restrict__ avs, const float* __restrict__ avd,
    ushort* __restrict__ Hb, float* __restrict__ os, float* __restrict__ od,
    int M, int NN) {
  constexpr int BM = 128, BK = 64, K = 768, KA = 512;
  __shared__ ushort As[BM * BK];
  __shared__ ushort Bs[BN * BK];
  const int t = threadIdx.x, l = t & 63, w = t >> 6;
  const int l15 = l & 15, l4 = l >> 4;
  const int m0 = blockIdx.y * BM, n0 = blockIdx.x * BN;
  const int wr = w >> 1, wc = w & 1;
  f32x4 acc[4][NF];
#pragma unroll
  for (int m = 0; m < 4; ++m)
#pragma unroll
    for (int n = 0; n < NF; ++n) acc[m][n] = (f32x4){0.f, 0.f, 0.f, 0.f};

  for (int kk = 0; kk < K; kk += BK) {
    const int ka = (kk < KA) ? kk : kk - KA;
    __syncthreads();
#pragma unroll
    for (int i = 0; i < 4; ++i) {  // A tile: 16 wave-chunks of 1KB
      int q = w * 4 + i;
      int c = q * 64 + l;
      int row = c >> 3, k8 = c & 7;
      int k8s = k8 ^ (row & 7);
      gload16(&A[(size_t)(m0 + row) * KA + ka + k8s * 8], &As[q * 512]);
    }
    constexpr int BCHW = (BN * 8 / 64) / 4;
#pragma unroll
    for (int i = 0; i < BCHW; ++i) {
      int q = w * BCHW + i;
      int c = q * 64 + l;
      int col = c >> 3, k8 = c & 7;
      int k8s = k8 ^ (col & 7);
      gload16(&Bt[(size_t)(n0 + col) * K + kk + k8s * 8], &Bs[q * 512]);
    }
    __syncthreads();
#pragma unroll
    for (int ks = 0; ks < 2; ++ks) {
      int kb = ks * 4 + l4;
      short8v af[4], bfr[NF];
#pragma unroll
      for (int m = 0; m < 4; ++m) {
        int row = wr * 64 + m * 16 + l15;
        af[m] = *(const short8v*)&As[row * 64 + (kb ^ (row & 7)) * 8];
      }
#pragma unroll
      for (int n = 0; n < NF; ++n) {
        int col = wc * (NF * 16) + n * 16 + l15;
        bfr[n] = *(const short8v*)&Bs[col * 64 + (kb ^ (col & 7)) * 8];
      }
#pragma unroll
      for (int m = 0; m < 4; ++m)
#pragma unroll
        for (int n = 0; n < NF; ++n)
          acc[m][n] = __builtin_amdgcn_mfma_f32_16x16x32_bf16(af[m], bfr[n], acc[m][n], 0, 0, 0);
    }
  }
  // ---- epilogue: bf16 output copy ----
#pragma unroll
  for (int m = 0; m < 4; ++m) {
    int rbase = m0 + wr * 64 + m * 16 + l4 * 4;
#pragma unroll
    for (int n = 0; n < NF; ++n) {
      int c = wc * (NF * 16) + n * 16 + l15;  // block-local col
      int gcol = IL ? (((n0 + c) & 63) * 4 + ((n0 + c) >> 6)) : (n0 + c);
#pragma unroll
      for (int r = 0; r < 4; ++r) {
        int row = rbase + r;
        if (row < M) Hb[(size_t)row * NN + gcol] = f2bf(acc[m][n][r]);
      }
    }
  }
  // ---- epilogue: attention dots ----
  float cs[NF], cd[NF];
#pragma unroll
  for (int n = 0; n < NF; ++n) {
    int gc = n0 + wc * (NF * 16) + n * 16 + l15;
    cs[n] = avs[gc];
    cd[n] = avd[gc];
  }
  const int H = NN >> 6;
  const int head = (n0 + wc * (NF * 16)) >> 6;
#pragma unroll
  for (int m = 0; m < 4; ++m) {
#pragma unroll
    for (int r = 0; r < 4; ++r) {
      float ps = 0.f, pd = 0.f;
#pragma unroll
      for (int n = 0; n < NF; ++n) { ps += acc[m][n][r] * cs[n]; pd += acc[m][n][r] * cd[n]; }
#pragma unroll
      for (int off = 1; off < 16; off <<= 1) {
        ps += __shfl_xor(ps, off, 64);
        pd += __shfl_xor(pd, off, 64);
      }
      if (l15 == 0) {
        int row = m0 + wr * 64 + m * 16 + l4 * 4 + r;
        if (row < M) {
          if (NF == 4) {
            os[(size_t)row * H + head] = ps;
            od[(size_t)row * H + head] = pd;
          } else {
            atomicAdd(&os[row], ps);
            atomicAdd(&od[row], pd);
          }
        }
      }
    }
  }
}

// ---------------- CSR build ----------------
__global__ void hist_kernel(const int* __restrict__ dst, int* __restrict__ counts,
                            int E, int Etot) {
  int e = blockIdx.x * blockDim.x + threadIdx.x;
  if (e >= Etot) return;
  int d = (e < E) ? dst[e] : (e - E);
  atomicAdd(&counts[d], 1);
}

__global__ __launch_bounds__(1024) void scan_kernel(const int* __restrict__ counts,
                                                    int* __restrict__ offsets, int n) {
  __shared__ int wsums[16];
  int t = threadIdx.x, lane = t & 63, w = t >> 6;
  int per = (n + 1023) >> 10;
  int s0 = t * per;
  int s1 = min(s0 + per, n);
  int s = 0;
  for (int i = s0; i < s1; ++i) s += counts[i];
  int x = s;
#pragma unroll
  for (int off = 1; off < 64; off <<= 1) {
    int y = __shfl_up(x, off, 64);
    if (lane >= off) x += y;
  }
  if (lane == 63) wsums[w] = x;
  __syncthreads();
  int wpre = 0;
  for (int i = 0; i < w; ++i) wpre += wsums[i];
  int run = wpre + x - s;  // exclusive prefix
  for (int i = s0; i < s1; ++i) { offsets[i] = run; run += counts[i]; }
  if (t == 1023) offsets[n] = run;
}

__global__ void scatter_kernel(const int* __restrict__ src, const int* __restrict__ dst,
    const int* __restrict__ offsets, int* __restrict__ cursor,
    int* __restrict__ src_sorted, int E, int Etot) {
  int e = blockIdx.x * blockDim.x + threadIdx.x;
  if (e >= Etot) return;
  int s = (e < E) ? src[e] : (e - E);
  int d = (e < E) ? dst[e] : (e - E);
  int pos = offsets[d] + atomicAdd(&cursor[d], 1);
  src_sorted[pos] = s;
}

// ---------------- aggregation layer 1 ----------------------------------------
// h1b interleaved: [row][feat*4 + head]. Edge p-work lane-parallel, broadcast
// via shuffles. No max subtraction (logits bounded; softmax shift-invariant).
__global__ __launch_bounds__(256) void agg1_kernel(const ushort* __restrict__ h1b,
    const float* __restrict__ as1, const float* __restrict__ ad1,
    const int* __restrict__ offsets, const int* __restrict__ src_sorted,
    const float* __restrict__ b1, ushort* __restrict__ A2, int N, int Mpad) {
  int wid = (blockIdx.x << 2) + (threadIdx.x >> 6);
  int lane = threadIdx.x & 63;
  if (wid >= Mpad) return;
  size_t ab = (size_t)wid * 512;
  if (wid >= N) {
#pragma unroll
    for (int i = 0; i < 8; ++i) A2[ab + i * 64 + lane] = 0;
    return;
  }
  float4 ah = *(const float4*)&ad1[(size_t)wid * 4];
  int st = offsets[wid], en = offsets[wid + 1];
  float acc0 = 0.f, acc1 = 0.f, acc2 = 0.f, acc3 = 0.f;
  float ds0 = 0.f, ds1 = 0.f, ds2 = 0.f, ds3 = 0.f;
  for (int c = st; c < en; c += 64) {
    int mye = c + lane;
    float p0 = 0.f, p1 = 0.f, p2 = 0.f, p3 = 0.f;
    int smy = 0;
    if (mye < en) {
      smy = src_sorted[mye];
      float4 a4 = *(const float4*)&as1[(size_t)smy * 4];
      p0 = __expf(lrelu(a4.x + ah.x));
      p1 = __expf(lrelu(a4.y + ah.y));
      p2 = __expf(lrelu(a4.z + ah.z));
      p3 = __expf(lrelu(a4.w + ah.w));
    }
    ds0 += p0; ds1 += p1; ds2 += p2; ds3 += p3;
    int cnt = min(64, en - c);
    for (int e = 0; e < cnt; ++e) {
      int s = __shfl(smy, e, 64);
      float q0 = __shfl(p0, e, 64);
      float q1 = __shfl(p1, e, 64);
      float q2 = __shfl(p2, e, 64);
      float q3 = __shfl(p3, e, 64);
      ushort4 hv = *(const ushort4*)&h1b[(size_t)s * 256 + lane * 4];
      acc0 += q0 * bf2f(hv.x);
      acc1 += q1 * bf2f(hv.y);
      acc2 += q2 * bf2f(hv.z);
      acc3 += q3 * bf2f(hv.w);
    }
  }
#pragma unroll
  for (int off = 32; off > 0; off >>= 1) {
    ds0 += __shfl_xor(ds0, off, 64);
    ds1 += __shfl_xor(ds1, off, 64);
    ds2 += __shfl_xor(ds2, off, 64);
    ds3 += __shfl_xor(ds3, off, 64);
  }
  float v[4];
  v[0] = fmaxf(acc0 / (ds0 + 1e-16f) + b1[lane], 0.f);
  v[1] = fmaxf(acc1 / (ds1 + 1e-16f) + b1[64 + lane], 0.f);
  v[2] = fmaxf(acc2 / (ds2 + 1e-16f) + b1[128 + lane], 0.f);
  v[3] = fmaxf(acc3 / (ds3 + 1e-16f) + b1[192 + lane], 0.f);
#pragma unroll
  for (int h = 0; h < 4; ++h) {
    ushort hi = f2bf(v[h]);
    ushort lo = f2bf(v[h] - bf2f(hi));
    A2[ab + h * 64 + lane] = hi;
    A2[ab + 256 + h * 64 + lane] = lo;
  }
}

// ---------------- aggregation layer 2 ----------------------------------------
__global__ __launch_bounds__(256) void agg2_kernel(const ushort* __restrict__ h2b,
    const float* __restrict__ as2, const float* __restrict__ ad2,
    const int* __restrict__ offsets, const int* __restrict__ src_sorted,
    const float* __restrict__ b2, float* __restrict__ out, int N) {
  int wid = (blockIdx.x << 2) + (threadIdx.x >> 6);
  int lane = threadIdx.x & 63;
  if (wid >= N) return;
  float ah = ad2[wid];
  int st = offsets[wid], en = offsets[wid + 1];
  float acc = 0.f, ds = 0.f;
  for (int c = st; c < en; c += 64) {
    int mye = c + lane;
    float p = 0.f;
    int smy = 0;
    if (mye < en) {
      smy = src_sorted[mye];
      p = __expf(lrelu(as2[smy] + ah));
    }
    ds += p;
    int cnt = min(64, en - c);
    for (int e = 0; e < cnt; ++e) {
      int s = __shfl(smy, e, 64);
      float q = __shfl(p, e, 64);
      acc += q * bf2f(h2b[(size_t)s * 64 + lane]);
    }
  }
#pragma unroll
  for (int off = 32; off > 0; off >>= 1) ds += __shfl_xor(ds, off, 64);
  out[(size_t)wid * 64 + lane] = acc / (ds + 1e-16f) + b2[lane];
}

// ---------------- launch ----------------
extern "C" void kernel_launch(void* const* d_in, const int* in_sizes, int n_in,
                              void* d_out, int out_size, void* d_ws, size_t ws_size,
                              hipStream_t stream) {
  const float* x      = (const float*)d_in[0];
  const int*   ei     = (const int*)d_in[1];
  const float* W1     = (const float*)d_in[2];
  const float* a_src1 = (const float*)d_in[3];
  const float* a_dst1 = (const float*)d_in[4];
  const float* b1     = (const float*)d_in[5];
  const float* W2     = (const float*)d_in[6];
  const float* a_src2 = (const float*)d_in[7];
  const float* a_dst2 = (const float*)d_in[8];
  const float* b2     = (const float*)d_in[9];
  float* out = (float*)d_out;

  const int IN = 256, HD = 256, D2 = 64;
  const int N = in_sizes[0] / IN;
  const int E = in_sizes[1] / 2;
  const int Etot = E + N;
  const int Mpad = ((N + 127) / 128) * 128;
  const int* srcp = ei;
  const int* dstp = ei + E;

  uintptr_t base = (uintptr_t)d_ws;
  auto alloc_bytes = [&](size_t nbytes) -> void* {
    void* p = (void*)base;
    base += (nbytes + 255) & ~(size_t)255;
    return p;
  };
  ushort* A1       = (ushort*)alloc_bytes((size_t)Mpad * 512 * 2);
  ushort* A2       = (ushort*)alloc_bytes((size_t)Mpad * 512 * 2);
  ushort* h1b      = (ushort*)alloc_bytes((size_t)N * HD * 2);
  ushort* h2b      = (ushort*)alloc_bytes((size_t)N * D2 * 2);
  ushort* B1t      = (ushort*)alloc_bytes((size_t)HD * 768 * 2);
  ushort* B2t      = (ushort*)alloc_bytes((size_t)D2 * 768 * 2);
  float* as1       = (float*)alloc_bytes((size_t)N * 4 * 4);
  float* ad1       = (float*)alloc_bytes((size_t)N * 4 * 4);
  // zero-init region start
  float* as2       = (float*)alloc_bytes((size_t)N * 4);
  float* ad2       = (float*)alloc_bytes((size_t)N * 4);
  int* counts      = (int*)alloc_bytes((size_t)(N + 1) * 4);
  int* cursor      = (int*)alloc_bytes((size_t)N * 4);
  uintptr_t zero_end = base;
  // zero-init region end
  int* offsets     = (int*)alloc_bytes((size_t)(N + 1) * 4);
  int* src_sorted  = (int*)alloc_bytes((size_t)Etot * 4);

  hipMemsetAsync((void*)as2, 0, zero_end - (uintptr_t)as2, stream);

  const int nwb  = (N + 3) / 4;
  const int nwbp = (Mpad + 3) / 4;
  const int neb  = (Etot + 255) / 256;

  // packing
  pack_x_kernel<<<(Mpad * 256 + 255) / 256, 256, 0, stream>>>(x, A1, N, Mpad);
  pack_w_kernel<<<(256 * HD + 255) / 256, 256, 0, stream>>>(W1, B1t, HD);
  pack_w_kernel<<<(256 * D2 + 255) / 256, 256, 0, stream>>>(W2, B2t, D2);
  // CSR (independent of layer 1)
  hist_kernel<<<neb, 256, 0, stream>>>(dstp, counts, E, Etot);
  scan_kernel<<<1, 1024, 0, stream>>>(counts, offsets, N);
  scatter_kernel<<<neb, 256, 0, stream>>>(srcp, dstp, offsets, cursor, src_sorted, E, Etot);
  // layer 1
  gemm_mfma<128, 4, true><<<dim3(HD / 128, Mpad / 128), 256, 0, stream>>>(
      A1, B1t, a_src1, a_dst1, h1b, as1, ad1, N, HD);
  agg1_kernel<<<nwbp, 256, 0, stream>>>(h1b, as1, ad1, offsets, src_sorted, b1, A2, N, Mpad);
  // layer 2
  gemm_mfma<64, 2, false><<<dim3(D2 / 64, Mpad / 128), 256, 0, stream>>>(
      A2, B2t, a_src2, a_dst2, h2b, as2, ad2, N, D2);
  agg2_kernel<<<nwb, 256, 0, stream>>>(h2b, as2, ad2, offsets, src_sorted, b2, out, N);
}

// Round 5
// 353.092 us; speedup vs baseline: 1.8972x; 1.1059x over previous
//
#include <hip/hip_runtime.h>
#include <hip/hip_bf16.h>

typedef __attribute__((ext_vector_type(8))) short short8v;
typedef __attribute__((ext_vector_type(4))) float f32x4;

// ---------------- helpers ----------------
__device__ __forceinline__ float lrelu(float x) { return x > 0.f ? x : 0.2f * x; }
__device__ __forceinline__ ushort f2bf(float v) {
  __hip_bfloat16 b = __float2bfloat16(v);
  return *(ushort*)&b;
}
__device__ __forceinline__ float bf2f(ushort u) {
  return __uint_as_float(((unsigned)u) << 16);
}
__device__ __forceinline__ void gload16(const ushort* g, ushort* l) {
  __builtin_amdgcn_global_load_lds((const __attribute__((address_space(1))) void*)g,
                                   (__attribute__((address_space(3))) void*)l, 16, 0, 0);
}

// ---------------- pack kernels (f32 -> bf16 hi/lo split) ----------------
__global__ __launch_bounds__(256) void pack_x_kernel(const float* __restrict__ x,
    ushort* __restrict__ A, int N, int Mpad) {
  int idx = blockIdx.x * 256 + threadIdx.x;
  if (idx >= Mpad * 256) return;
  int row = idx >> 8, c = idx & 255;
  float v = (row < N) ? x[idx] : 0.f;
  ushort hi = f2bf(v);
  ushort lo = f2bf(v - bf2f(hi));
  A[(size_t)row * 512 + c] = hi;
  A[(size_t)row * 512 + 256 + c] = lo;
}

__global__ __launch_bounds__(256) void pack_w_kernel(const float* __restrict__ W,
    ushort* __restrict__ Bt, int NN) {
  int idx = blockIdx.x * 256 + threadIdx.x;  // over 256*NN, W is [256][NN]
  if (idx >= 256 * NN) return;
  int k = idx / NN, col = idx % NN;
  float v = W[idx];
  ushort hi = f2bf(v), lo = f2bf(v - bf2f(hi));
  size_t b = (size_t)col * 768;
  Bt[b + k] = hi;
  Bt[b + 256 + k] = hi;
  Bt[b + 512 + k] = lo;
}

// ---------------- MFMA GEMM with fused bf16-output + attention dots ----------
// IL=true: Hb written interleaved as [row][feat*4 + head] (NN=256, 4 heads).
template<int BN, int NF, bool IL>
__global__ __launch_bounds__(256) void gemm_mfma(
    const ushort* __restrict__ A, const ushort* __restrict__ Bt,
    const float* __restrict__ avs, const float* __restrict__ avd,
    ushort* __restrict__ Hb, float* __restrict__ os, float* __restrict__ od,
    int M, int NN) {
  constexpr int BM = 128, BK = 64, K = 768, KA = 512;
  __shared__ ushort As[BM * BK];
  __shared__ ushort Bs[BN * BK];
  const int t = threadIdx.x, l = t & 63, w = t >> 6;
  const int l15 = l & 15, l4 = l >> 4;
  const int m0 = blockIdx.y * BM, n0 = blockIdx.x * BN;
  const int wr = w >> 1, wc = w & 1;
  f32x4 acc[4][NF];
#pragma unroll
  for (int m = 0; m < 4; ++m)
#pragma unroll
    for (int n = 0; n < NF; ++n) acc[m][n] = (f32x4){0.f, 0.f, 0.f, 0.f};

  for (int kk = 0; kk < K; kk += BK) {
    const int ka = (kk < KA) ? kk : kk - KA;
    __syncthreads();
#pragma unroll
    for (int i = 0; i < 4; ++i) {  // A tile: 16 wave-chunks of 1KB
      int q = w * 4 + i;
      int c = q * 64 + l;
      int row = c >> 3, k8 = c & 7;
      int k8s = k8 ^ (row & 7);
      gload16(&A[(size_t)(m0 + row) * KA + ka + k8s * 8], &As[q * 512]);
    }
    constexpr int BCHW = (BN * 8 / 64) / 4;
#pragma unroll
    for (int i = 0; i < BCHW; ++i) {
      int q = w * BCHW + i;
      int c = q * 64 + l;
      int col = c >> 3, k8 = c & 7;
      int k8s = k8 ^ (col & 7);
      gload16(&Bt[(size_t)(n0 + col) * K + kk + k8s * 8], &Bs[q * 512]);
    }
    __syncthreads();
#pragma unroll
    for (int ks = 0; ks < 2; ++ks) {
      int kb = ks * 4 + l4;
      short8v af[4], bfr[NF];
#pragma unroll
      for (int m = 0; m < 4; ++m) {
        int row = wr * 64 + m * 16 + l15;
        af[m] = *(const short8v*)&As[row * 64 + (kb ^ (row & 7)) * 8];
      }
#pragma unroll
      for (int n = 0; n < NF; ++n) {
        int col = wc * (NF * 16) + n * 16 + l15;
        bfr[n] = *(const short8v*)&Bs[col * 64 + (kb ^ (col & 7)) * 8];
      }
#pragma unroll
      for (int m = 0; m < 4; ++m)
#pragma unroll
        for (int n = 0; n < NF; ++n)
          acc[m][n] = __builtin_amdgcn_mfma_f32_16x16x32_bf16(af[m], bfr[n], acc[m][n], 0, 0, 0);
    }
  }
  // ---- epilogue: bf16 output copy ----
#pragma unroll
  for (int m = 0; m < 4; ++m) {
    int rbase = m0 + wr * 64 + m * 16 + l4 * 4;
#pragma unroll
    for (int n = 0; n < NF; ++n) {
      int c = wc * (NF * 16) + n * 16 + l15;  // block-local col
      int gcol = IL ? (((n0 + c) & 63) * 4 + ((n0 + c) >> 6)) : (n0 + c);
#pragma unroll
      for (int r = 0; r < 4; ++r) {
        int row = rbase + r;
        if (row < M) Hb[(size_t)row * NN + gcol] = f2bf(acc[m][n][r]);
      }
    }
  }
  // ---- epilogue: attention dots ----
  float cs[NF], cd[NF];
#pragma unroll
  for (int n = 0; n < NF; ++n) {
    int gc = n0 + wc * (NF * 16) + n * 16 + l15;
    cs[n] = avs[gc];
    cd[n] = avd[gc];
  }
  const int H = NN >> 6;
  const int head = (n0 + wc * (NF * 16)) >> 6;
#pragma unroll
  for (int m = 0; m < 4; ++m) {
#pragma unroll
    for (int r = 0; r < 4; ++r) {
      float ps = 0.f, pd = 0.f;
#pragma unroll
      for (int n = 0; n < NF; ++n) { ps += acc[m][n][r] * cs[n]; pd += acc[m][n][r] * cd[n]; }
#pragma unroll
      for (int off = 1; off < 16; off <<= 1) {
        ps += __shfl_xor(ps, off, 64);
        pd += __shfl_xor(pd, off, 64);
      }
      if (l15 == 0) {
        int row = m0 + wr * 64 + m * 16 + l4 * 4 + r;
        if (row < M) {
          if (NF == 4) {
            os[(size_t)row * H + head] = ps;
            od[(size_t)row * H + head] = pd;
          } else {
            atomicAdd(&os[row], ps);
            atomicAdd(&od[row], pd);
          }
        }
      }
    }
  }
}

// ---------------- CSR build ----------------
__global__ void hist_kernel(const int* __restrict__ dst, int* __restrict__ counts,
                            int E, int Etot) {
  int e = blockIdx.x * blockDim.x + threadIdx.x;
  if (e >= Etot) return;
  int d = (e < E) ? dst[e] : (e - E);
  atomicAdd(&counts[d], 1);
}

__global__ __launch_bounds__(1024) void scan_kernel(const int* __restrict__ counts,
                                                    int* __restrict__ offsets, int n) {
  __shared__ int wsums[16];
  int t = threadIdx.x, lane = t & 63, w = t >> 6;
  int per = (n + 1023) >> 10;
  int s0 = t * per;
  int s1 = min(s0 + per, n);
  int s = 0;
  for (int i = s0; i < s1; ++i) s += counts[i];
  int x = s;
#pragma unroll
  for (int off = 1; off < 64; off <<= 1) {
    int y = __shfl_up(x, off, 64);
    if (lane >= off) x += y;
  }
  if (lane == 63) wsums[w] = x;
  __syncthreads();
  int wpre = 0;
  for (int i = 0; i < w; ++i) wpre += wsums[i];
  int run = wpre + x - s;  // exclusive prefix
  for (int i = s0; i < s1; ++i) { offsets[i] = run; run += counts[i]; }
  if (t == 1023) offsets[n] = run;
}

__global__ void scatter_kernel(const int* __restrict__ src, const int* __restrict__ dst,
    const int* __restrict__ offsets, int* __restrict__ cursor,
    int* __restrict__ src_sorted, int E, int Etot) {
  int e = blockIdx.x * blockDim.x + threadIdx.x;
  if (e >= Etot) return;
  int s = (e < E) ? src[e] : (e - E);
  int d = (e < E) ? dst[e] : (e - E);
  int pos = offsets[d] + atomicAdd(&cursor[d], 1);
  src_sorted[pos] = s;
}

// ---------------- aggregation layer 1 ----------------------------------------
// h1b interleaved: [row][feat*4 + head]. Per 64-edge chunk: lane-parallel p
// computation staged to LDS, then 4x-unrolled gather loop (uniform-address LDS
// broadcasts for p/src, 4 independent row loads in flight).
__global__ __launch_bounds__(256) void agg1_kernel(const ushort* __restrict__ h1b,
    const float* __restrict__ as1, const float* __restrict__ ad1,
    const int* __restrict__ offsets, const int* __restrict__ src_sorted,
    const float* __restrict__ b1, ushort* __restrict__ A2, int N, int Mpad) {
  __shared__ float4 pl[4][64];
  __shared__ alignas(16) int sl[4][64];
  int wv = threadIdx.x >> 6;
  int wid = (blockIdx.x << 2) + wv;
  int lane = threadIdx.x & 63;
  if (wid >= Mpad) return;
  size_t ab = (size_t)wid * 512;
  if (wid >= N) {
#pragma unroll
    for (int i = 0; i < 8; ++i) A2[ab + i * 64 + lane] = 0;
    return;
  }
  float4 ah = *(const float4*)&ad1[(size_t)wid * 4];
  int st = offsets[wid], en = offsets[wid + 1];
  float acc0 = 0.f, acc1 = 0.f, acc2 = 0.f, acc3 = 0.f;
  float ds0 = 0.f, ds1 = 0.f, ds2 = 0.f, ds3 = 0.f;
  const ushort* __restrict__ hb = h1b;
  for (int c = st; c < en; c += 64) {
    int mye = c + lane;
    float4 p = make_float4(0.f, 0.f, 0.f, 0.f);
    int smy = 0;
    if (mye < en) {
      smy = src_sorted[mye];
      float4 a4 = *(const float4*)&as1[(size_t)smy * 4];
      p.x = __expf(lrelu(a4.x + ah.x));
      p.y = __expf(lrelu(a4.y + ah.y));
      p.z = __expf(lrelu(a4.z + ah.z));
      p.w = __expf(lrelu(a4.w + ah.w));
    }
    ds0 += p.x; ds1 += p.y; ds2 += p.z; ds3 += p.w;
    pl[wv][lane] = p;
    sl[wv][lane] = smy;
    int cnt = min(64, en - c);
    int e = 0;
    for (; e + 4 <= cnt; e += 4) {
      int4 s4 = *(const int4*)&sl[wv][e];       // uniform addr -> broadcast
      float4 q0 = pl[wv][e + 0];
      float4 q1 = pl[wv][e + 1];
      float4 q2 = pl[wv][e + 2];
      float4 q3 = pl[wv][e + 3];
      ushort4 h0 = *(const ushort4*)&hb[(size_t)s4.x * 256 + lane * 4];
      ushort4 h1 = *(const ushort4*)&hb[(size_t)s4.y * 256 + lane * 4];
      ushort4 h2 = *(const ushort4*)&hb[(size_t)s4.z * 256 + lane * 4];
      ushort4 h3 = *(const ushort4*)&hb[(size_t)s4.w * 256 + lane * 4];
      acc0 += q0.x * bf2f(h0.x); acc1 += q0.y * bf2f(h0.y);
      acc2 += q0.z * bf2f(h0.z); acc3 += q0.w * bf2f(h0.w);
      acc0 += q1.x * bf2f(h1.x); acc1 += q1.y * bf2f(h1.y);
      acc2 += q1.z * bf2f(h1.z); acc3 += q1.w * bf2f(h1.w);
      acc0 += q2.x * bf2f(h2.x); acc1 += q2.y * bf2f(h2.y);
      acc2 += q2.z * bf2f(h2.z); acc3 += q2.w * bf2f(h2.w);
      acc0 += q3.x * bf2f(h3.x); acc1 += q3.y * bf2f(h3.y);
      acc2 += q3.z * bf2f(h3.z); acc3 += q3.w * bf2f(h3.w);
    }
    for (; e < cnt; ++e) {
      int s = sl[wv][e];
      float4 q = pl[wv][e];
      ushort4 hv = *(const ushort4*)&hb[(size_t)s * 256 + lane * 4];
      acc0 += q.x * bf2f(hv.x);
      acc1 += q.y * bf2f(hv.y);
      acc2 += q.z * bf2f(hv.z);
      acc3 += q.w * bf2f(hv.w);
    }
  }
#pragma unroll
  for (int off = 32; off > 0; off >>= 1) {
    ds0 += __shfl_xor(ds0, off, 64);
    ds1 += __shfl_xor(ds1, off, 64);
    ds2 += __shfl_xor(ds2, off, 64);
    ds3 += __shfl_xor(ds3, off, 64);
  }
  float v[4];
  v[0] = fmaxf(acc0 / (ds0 + 1e-16f) + b1[lane], 0.f);
  v[1] = fmaxf(acc1 / (ds1 + 1e-16f) + b1[64 + lane], 0.f);
  v[2] = fmaxf(acc2 / (ds2 + 1e-16f) + b1[128 + lane], 0.f);
  v[3] = fmaxf(acc3 / (ds3 + 1e-16f) + b1[192 + lane], 0.f);
#pragma unroll
  for (int h = 0; h < 4; ++h) {
    ushort hi = f2bf(v[h]);
    ushort lo = f2bf(v[h] - bf2f(hi));
    A2[ab + h * 64 + lane] = hi;
    A2[ab + 256 + h * 64 + lane] = lo;
  }
}

// ---------------- aggregation layer 2 ----------------------------------------
__global__ __launch_bounds__(256) void agg2_kernel(const ushort* __restrict__ h2b,
    const float* __restrict__ as2, const float* __restrict__ ad2,
    const int* __restrict__ offsets, const int* __restrict__ src_sorted,
    const float* __restrict__ b2, float* __restrict__ out, int N) {
  __shared__ float pl[4][64];
  __shared__ alignas(16) int sl[4][64];
  int wv = threadIdx.x >> 6;
  int wid = (blockIdx.x << 2) + wv;
  int lane = threadIdx.x & 63;
  if (wid >= N) return;
  float ah = ad2[wid];
  int st = offsets[wid], en = offsets[wid + 1];
  float acc = 0.f, ds = 0.f;
  for (int c = st; c < en; c += 64) {
    int mye = c + lane;
    float p = 0.f;
    int smy = 0;
    if (mye < en) {
      smy = src_sorted[mye];
      p = __expf(lrelu(as2[smy] + ah));
    }
    ds += p;
    pl[wv][lane] = p;
    sl[wv][lane] = smy;
    int cnt = min(64, en - c);
    int e = 0;
    for (; e + 4 <= cnt; e += 4) {
      int4 s4 = *(const int4*)&sl[wv][e];
      float4 q4 = *(const float4*)&pl[wv][e];
      ushort h0 = h2b[(size_t)s4.x * 64 + lane];
      ushort h1 = h2b[(size_t)s4.y * 64 + lane];
      ushort h2 = h2b[(size_t)s4.z * 64 + lane];
      ushort h3 = h2b[(size_t)s4.w * 64 + lane];
      acc += q4.x * bf2f(h0) + q4.y * bf2f(h1) + q4.z * bf2f(h2) + q4.w * bf2f(h3);
    }
    for (; e < cnt; ++e) {
      acc += pl[wv][e] * bf2f(h2b[(size_t)sl[wv][e] * 64 + lane]);
    }
  }
#pragma unroll
  for (int off = 32; off > 0; off >>= 1) ds += __shfl_xor(ds, off, 64);
  out[(size_t)wid * 64 + lane] = acc / (ds + 1e-16f) + b2[lane];
}

// ---------------- launch ----------------
extern "C" void kernel_launch(void* const* d_in, const int* in_sizes, int n_in,
                              void* d_out, int out_size, void* d_ws, size_t ws_size,
                              hipStream_t stream) {
  const float* x      = (const float*)d_in[0];
  const int*   ei     = (const int*)d_in[1];
  const float* W1     = (const float*)d_in[2];
  const float* a_src1 = (const float*)d_in[3];
  const float* a_dst1 = (const float*)d_in[4];
  const float* b1     = (const float*)d_in[5];
  const float* W2     = (const float*)d_in[6];
  const float* a_src2 = (const float*)d_in[7];
  const float* a_dst2 = (const float*)d_in[8];
  const float* b2     = (const float*)d_in[9];
  float* out = (float*)d_out;

  const int IN = 256, HD = 256, D2 = 64;
  const int N = in_sizes[0] / IN;
  const int E = in_sizes[1] / 2;
  const int Etot = E + N;
  const int Mpad = ((N + 127) / 128) * 128;
  const int* srcp = ei;
  const int* dstp = ei + E;

  uintptr_t base = (uintptr_t)d_ws;
  auto alloc_bytes = [&](size_t nbytes) -> void* {
    void* p = (void*)base;
    base += (nbytes + 255) & ~(size_t)255;
    return p;
  };
  ushort* A1       = (ushort*)alloc_bytes((size_t)Mpad * 512 * 2);
  ushort* A2       = (ushort*)alloc_bytes((size_t)Mpad * 512 * 2);
  ushort* h1b      = (ushort*)alloc_bytes((size_t)N * HD * 2);
  ushort* h2b      = (ushort*)alloc_bytes((size_t)N * D2 * 2);
  ushort* B1t      = (ushort*)alloc_bytes((size_t)HD * 768 * 2);
  ushort* B2t      = (ushort*)alloc_bytes((size_t)D2 * 768 * 2);
  float* as1       = (float*)alloc_bytes((size_t)N * 4 * 4);
  float* ad1       = (float*)alloc_bytes((size_t)N * 4 * 4);
  // zero-init region start
  float* as2       = (float*)alloc_bytes((size_t)N * 4);
  float* ad2       = (float*)alloc_bytes((size_t)N * 4);
  int* counts      = (int*)alloc_bytes((size_t)(N + 1) * 4);
  int* cursor      = (int*)alloc_bytes((size_t)N * 4);
  uintptr_t zero_end = base;
  // zero-init region end
  int* offsets     = (int*)alloc_bytes((size_t)(N + 1) * 4);
  int* src_sorted  = (int*)alloc_bytes((size_t)Etot * 4);

  hipMemsetAsync((void*)as2, 0, zero_end - (uintptr_t)as2, stream);

  const int nwb  = (N + 3) / 4;
  const int nwbp = (Mpad + 3) / 4;
  const int neb  = (Etot + 255) / 256;

  // packing
  pack_x_kernel<<<(Mpad * 256 + 255) / 256, 256, 0, stream>>>(x, A1, N, Mpad);
  pack_w_kernel<<<(256 * HD + 255) / 256, 256, 0, stream>>>(W1, B1t, HD);
  pack_w_kernel<<<(256 * D2 + 255) / 256, 256, 0, stream>>>(W2, B2t, D2);
  // CSR (independent of layer 1)
  hist_kernel<<<neb, 256, 0, stream>>>(dstp, counts, E, Etot);
  scan_kernel<<<1, 1024, 0, stream>>>(counts, offsets, N);
  scatter_kernel<<<neb, 256, 0, stream>>>(srcp, dstp, offsets, cursor, src_sorted, E, Etot);
  // layer 1
  gemm_mfma<128, 4, true><<<dim3(HD / 128, Mpad / 128), 256, 0, stream>>>(
      A1, B1t, a_src1, a_dst1, h1b, as1, ad1, N, HD);
  agg1_kernel<<<nwbp, 256, 0, stream>>>(h1b, as1, ad1, offsets, src_sorted, b1, A2, N, Mpad);
  // layer 2
  gemm_mfma<64, 2, false><<<dim3(D2 / 64, Mpad / 128), 256, 0, stream>>>(
      A2, B2t, a_src2, a_dst2, h2b, as2, ad2, N, D2);
  agg2_kernel<<<nwb, 256, 0, stream>>>(h2b, as2, ad2, offsets, src_sorted, b2, out, N);
}

// Round 6
// 299.903 us; speedup vs baseline: 2.2337x; 1.1774x over previous
//
#include <hip/hip_runtime.h>
#include <hip/hip_bf16.h>

typedef __attribute__((ext_vector_type(8))) short short8v;
typedef __attribute__((ext_vector_type(4))) float f32x4;

// ---------------- helpers ----------------
__device__ __forceinline__ float lrelu(float x) { return x > 0.f ? x : 0.2f * x; }
__device__ __forceinline__ ushort f2bf(float v) {
  __hip_bfloat16 b = __float2bfloat16(v);
  return *(ushort*)&b;
}
__device__ __forceinline__ float bf2f(ushort u) {
  return __uint_as_float(((unsigned)u) << 16);
}
__device__ __forceinline__ void gload16(const ushort* g, ushort* l) {
  __builtin_amdgcn_global_load_lds((const __attribute__((address_space(1))) void*)g,
                                   (__attribute__((address_space(3))) void*)l, 16, 0, 0);
}

// ---------------- pack kernels (f32 -> bf16 hi/lo split) ----------------
__global__ __launch_bounds__(256) void pack_x_kernel(const float* __restrict__ x,
    ushort* __restrict__ A, int N, int Mpad) {
  int idx = blockIdx.x * 256 + threadIdx.x;
  if (idx >= Mpad * 256) return;
  int row = idx >> 8, c = idx & 255;
  float v = (row < N) ? x[idx] : 0.f;
  ushort hi = f2bf(v);
  ushort lo = f2bf(v - bf2f(hi));
  A[(size_t)row * 512 + c] = hi;
  A[(size_t)row * 512 + 256 + c] = lo;
}

__global__ __launch_bounds__(256) void pack_w_kernel(const float* __restrict__ W,
    ushort* __restrict__ Bt, int NN) {
  int idx = blockIdx.x * 256 + threadIdx.x;  // over 256*NN, W is [256][NN]
  if (idx >= 256 * NN) return;
  int k = idx / NN, col = idx % NN;
  float v = W[idx];
  ushort hi = f2bf(v), lo = f2bf(v - bf2f(hi));
  size_t b = (size_t)col * 768;
  Bt[b + k] = hi;
  Bt[b + 256 + k] = hi;
  Bt[b + 512 + k] = lo;
}

// ---------------- MFMA GEMM with fused bf16-output + attention dots ----------
// IL=true: Hb written interleaved as [row][feat*4 + head] (NN=256, 4 heads).
template<int BN, int NF, bool IL>
__global__ __launch_bounds__(256) void gemm_mfma(
    const ushort* __restrict__ A, const ushort* __restrict__ Bt,
    const float* __restrict__ avs, const float* __restrict__ avd,
    ushort* __restrict__ Hb, float* __restrict__ os, float* __restrict__ od,
    int M, int NN) {
  constexpr int BM = 128, BK = 64, K = 768, KA = 512;
  __shared__ ushort As[BM * BK];
  __shared__ ushort Bs[BN * BK];
  const int t = threadIdx.x, l = t & 63, w = t >> 6;
  const int l15 = l & 15, l4 = l >> 4;
  const int m0 = blockIdx.y * BM, n0 = blockIdx.x * BN;
  const int wr = w >> 1, wc = w & 1;
  f32x4 acc[4][NF];
#pragma unroll
  for (int m = 0; m < 4; ++m)
#pragma unroll
    for (int n = 0; n < NF; ++n) acc[m][n] = (f32x4){0.f, 0.f, 0.f, 0.f};

  for (int kk = 0; kk < K; kk += BK) {
    const int ka = (kk < KA) ? kk : kk - KA;
    __syncthreads();
#pragma unroll
    for (int i = 0; i < 4; ++i) {  // A tile: 16 wave-chunks of 1KB
      int q = w * 4 + i;
      int c = q * 64 + l;
      int row = c >> 3, k8 = c & 7;
      int k8s = k8 ^ (row & 7);
      gload16(&A[(size_t)(m0 + row) * KA + ka + k8s * 8], &As[q * 512]);
    }
    constexpr int BCHW = (BN * 8 / 64) / 4;
#pragma unroll
    for (int i = 0; i < BCHW; ++i) {
      int q = w * BCHW + i;
      int c = q * 64 + l;
      int col = c >> 3, k8 = c & 7;
      int k8s = k8 ^ (col & 7);
      gload16(&Bt[(size_t)(n0 + col) * K + kk + k8s * 8], &Bs[q * 512]);
    }
    __syncthreads();
#pragma unroll
    for (int ks = 0; ks < 2; ++ks) {
      int kb = ks * 4 + l4;
      short8v af[4], bfr[NF];
#pragma unroll
      for (int m = 0; m < 4; ++m) {
        int row = wr * 64 + m * 16 + l15;
        af[m] = *(const short8v*)&As[row * 64 + (kb ^ (row & 7)) * 8];
      }
#pragma unroll
      for (int n = 0; n < NF; ++n) {
        int col = wc * (NF * 16) + n * 16 + l15;
        bfr[n] = *(const short8v*)&Bs[col * 64 + (kb ^ (col & 7)) * 8];
      }
#pragma unroll
      for (int m = 0; m < 4; ++m)
#pragma unroll
        for (int n = 0; n < NF; ++n)
          acc[m][n] = __builtin_amdgcn_mfma_f32_16x16x32_bf16(af[m], bfr[n], acc[m][n], 0, 0, 0);
    }
  }
  // ---- epilogue: bf16 output copy ----
#pragma unroll
  for (int m = 0; m < 4; ++m) {
    int rbase = m0 + wr * 64 + m * 16 + l4 * 4;
#pragma unroll
    for (int n = 0; n < NF; ++n) {
      int c = wc * (NF * 16) + n * 16 + l15;  // block-local col
      int gcol = IL ? (((n0 + c) & 63) * 4 + ((n0 + c) >> 6)) : (n0 + c);
#pragma unroll
      for (int r = 0; r < 4; ++r) {
        int row = rbase + r;
        if (row < M) Hb[(size_t)row * NN + gcol] = f2bf(acc[m][n][r]);
      }
    }
  }
  // ---- epilogue: attention dots ----
  float cs[NF], cd[NF];
#pragma unroll
  for (int n = 0; n < NF; ++n) {
    int gc = n0 + wc * (NF * 16) + n * 16 + l15;
    cs[n] = avs[gc];
    cd[n] = avd[gc];
  }
  const int H = NN >> 6;
  const int head = (n0 + wc * (NF * 16)) >> 6;
#pragma unroll
  for (int m = 0; m < 4; ++m) {
#pragma unroll
    for (int r = 0; r < 4; ++r) {
      float ps = 0.f, pd = 0.f;
#pragma unroll
      for (int n = 0; n < NF; ++n) { ps += acc[m][n][r] * cs[n]; pd += acc[m][n][r] * cd[n]; }
#pragma unroll
      for (int off = 1; off < 16; off <<= 1) {
        ps += __shfl_xor(ps, off, 64);
        pd += __shfl_xor(pd, off, 64);
      }
      if (l15 == 0) {
        int row = m0 + wr * 64 + m * 16 + l4 * 4 + r;
        if (row < M) {
          if (NF == 4) {
            os[(size_t)row * H + head] = ps;
            od[(size_t)row * H + head] = pd;
          } else {
            atomicAdd(&os[row], ps);
            atomicAdd(&od[row], pd);
          }
        }
      }
    }
  }
}

// ---------------- CSR build ----------------
__global__ void hist_kernel(const int* __restrict__ dst, int* __restrict__ counts,
                            int E, int Etot) {
  int e = blockIdx.x * blockDim.x + threadIdx.x;
  if (e >= Etot) return;
  int d = (e < E) ? dst[e] : (e - E);
  atomicAdd(&counts[d], 1);
}

// hierarchical scan: 2048 elems/block, coalesced, 3 tiny phases
static constexpr int SCB = 2048;

__global__ __launch_bounds__(256) void scan1_kernel(const int* __restrict__ counts,
    int* __restrict__ offsets, int* __restrict__ bsums, int n) {
  __shared__ int wsum[4];
  int t = threadIdx.x, lane = t & 63, w = t >> 6;
  int base = blockIdx.x * SCB + t * 8;
  int c[8];
  if (base + 7 < n) {
    int4 v0 = *(const int4*)&counts[base];
    int4 v1 = *(const int4*)&counts[base + 4];
    c[0] = v0.x; c[1] = v0.y; c[2] = v0.z; c[3] = v0.w;
    c[4] = v1.x; c[5] = v1.y; c[6] = v1.z; c[7] = v1.w;
  } else {
#pragma unroll
    for (int j = 0; j < 8; ++j) c[j] = (base + j < n) ? counts[base + j] : 0;
  }
  int ts = 0;
#pragma unroll
  for (int j = 0; j < 8; ++j) ts += c[j];
  int x = ts;
#pragma unroll
  for (int off = 1; off < 64; off <<= 1) {
    int y = __shfl_up(x, off, 64);
    if (lane >= off) x += y;
  }
  if (lane == 63) wsum[w] = x;
  __syncthreads();
  int wpre = 0;
  for (int ww = 0; ww < w; ++ww) wpre += wsum[ww];
  int ex = wpre + x - ts;  // exclusive prefix of this thread's first elem
  int o[8];
#pragma unroll
  for (int j = 0; j < 8; ++j) { o[j] = ex; ex += c[j]; }
  if (base + 7 < n) {
    *(int4*)&offsets[base] = make_int4(o[0], o[1], o[2], o[3]);
    *(int4*)&offsets[base + 4] = make_int4(o[4], o[5], o[6], o[7]);
  } else {
#pragma unroll
    for (int j = 0; j < 8; ++j) if (base + j < n) offsets[base + j] = o[j];
  }
  if (t == 255) bsums[blockIdx.x] = wpre + x;
}

__global__ __launch_bounds__(256) void scan2_kernel(const int* __restrict__ bsums,
    int* __restrict__ bbase, int nb) {
  __shared__ int wsum[4];
  int t = threadIdx.x, lane = t & 63, w = t >> 6;
  int v = (t < nb) ? bsums[t] : 0;
  int x = v;
#pragma unroll
  for (int off = 1; off < 64; off <<= 1) {
    int y = __shfl_up(x, off, 64);
    if (lane >= off) x += y;
  }
  if (lane == 63) wsum[w] = x;
  __syncthreads();
  int wpre = 0;
  for (int ww = 0; ww < w; ++ww) wpre += wsum[ww];
  if (t < nb) bbase[t] = wpre + x - v;
}

__global__ __launch_bounds__(256) void scan3_kernel(int* __restrict__ offsets,
    int* __restrict__ cursor, const int* __restrict__ bbase, int n, int total) {
  int t = threadIdx.x;
  int bb = bbase[blockIdx.x];
  int base = blockIdx.x * SCB + t * 8;
  if (base + 7 < n) {
    int4 v0 = *(const int4*)&offsets[base];
    int4 v1 = *(const int4*)&offsets[base + 4];
    v0.x += bb; v0.y += bb; v0.z += bb; v0.w += bb;
    v1.x += bb; v1.y += bb; v1.z += bb; v1.w += bb;
    *(int4*)&offsets[base] = v0;
    *(int4*)&offsets[base + 4] = v1;
    *(int4*)&cursor[base] = v0;
    *(int4*)&cursor[base + 4] = v1;
  } else {
#pragma unroll
    for (int j = 0; j < 8; ++j)
      if (base + j < n) {
        int vv = offsets[base + j] + bb;
        offsets[base + j] = vv;
        cursor[base + j] = vv;
      }
  }
  if (blockIdx.x == 0 && t == 0) offsets[n] = total;
}

__global__ void scatter_kernel(const int* __restrict__ src, const int* __restrict__ dst,
    int* __restrict__ cursor, int* __restrict__ src_sorted, int E, int Etot) {
  int e = blockIdx.x * blockDim.x + threadIdx.x;
  if (e >= Etot) return;
  int s = (e < E) ? src[e] : (e - E);
  int d = (e < E) ? dst[e] : (e - E);
  int pos = atomicAdd(&cursor[d], 1);
  src_sorted[pos] = s;
}

// ---------------- aggregation layer 1 ----------------------------------------
// h1b interleaved: [row][feat*4 + head]. Per 64-edge chunk: lane-parallel p
// computation staged to LDS, then 4x-unrolled gather loop (uniform-address LDS
// broadcasts for p/src, 4 independent row loads in flight).
__global__ __launch_bounds__(256) void agg1_kernel(const ushort* __restrict__ h1b,
    const float* __restrict__ as1, const float* __restrict__ ad1,
    const int* __restrict__ offsets, const int* __restrict__ src_sorted,
    const float* __restrict__ b1, ushort* __restrict__ A2, int N, int Mpad) {
  __shared__ float4 pl[4][64];
  __shared__ alignas(16) int sl[4][64];
  int wv = threadIdx.x >> 6;
  int wid = (blockIdx.x << 2) + wv;
  int lane = threadIdx.x & 63;
  if (wid >= Mpad) return;
  size_t ab = (size_t)wid * 512;
  if (wid >= N) {
#pragma unroll
    for (int i = 0; i < 8; ++i) A2[ab + i * 64 + lane] = 0;
    return;
  }
  float4 ah = *(const float4*)&ad1[(size_t)wid * 4];
  int st = offsets[wid], en = offsets[wid + 1];
  float acc0 = 0.f, acc1 = 0.f, acc2 = 0.f, acc3 = 0.f;
  float ds0 = 0.f, ds1 = 0.f, ds2 = 0.f, ds3 = 0.f;
  const ushort* __restrict__ hb = h1b;
  for (int c = st; c < en; c += 64) {
    int mye = c + lane;
    float4 p = make_float4(0.f, 0.f, 0.f, 0.f);
    int smy = 0;
    if (mye < en) {
      smy = src_sorted[mye];
      float4 a4 = *(const float4*)&as1[(size_t)smy * 4];
      p.x = __expf(lrelu(a4.x + ah.x));
      p.y = __expf(lrelu(a4.y + ah.y));
      p.z = __expf(lrelu(a4.z + ah.z));
      p.w = __expf(lrelu(a4.w + ah.w));
    }
    ds0 += p.x; ds1 += p.y; ds2 += p.z; ds3 += p.w;
    pl[wv][lane] = p;
    sl[wv][lane] = smy;
    int cnt = min(64, en - c);
    int e = 0;
    for (; e + 4 <= cnt; e += 4) {
      int4 s4 = *(const int4*)&sl[wv][e];       // uniform addr -> broadcast
      float4 q0 = pl[wv][e + 0];
      float4 q1 = pl[wv][e + 1];
      float4 q2 = pl[wv][e + 2];
      float4 q3 = pl[wv][e + 3];
      ushort4 h0 = *(const ushort4*)&hb[(size_t)s4.x * 256 + lane * 4];
      ushort4 h1 = *(const ushort4*)&hb[(size_t)s4.y * 256 + lane * 4];
      ushort4 h2 = *(const ushort4*)&hb[(size_t)s4.z * 256 + lane * 4];
      ushort4 h3 = *(const ushort4*)&hb[(size_t)s4.w * 256 + lane * 4];
      acc0 += q0.x * bf2f(h0.x); acc1 += q0.y * bf2f(h0.y);
      acc2 += q0.z * bf2f(h0.z); acc3 += q0.w * bf2f(h0.w);
      acc0 += q1.x * bf2f(h1.x); acc1 += q1.y * bf2f(h1.y);
      acc2 += q1.z * bf2f(h1.z); acc3 += q1.w * bf2f(h1.w);
      acc0 += q2.x * bf2f(h2.x); acc1 += q2.y * bf2f(h2.y);
      acc2 += q2.z * bf2f(h2.z); acc3 += q2.w * bf2f(h2.w);
      acc0 += q3.x * bf2f(h3.x); acc1 += q3.y * bf2f(h3.y);
      acc2 += q3.z * bf2f(h3.z); acc3 += q3.w * bf2f(h3.w);
    }
    for (; e < cnt; ++e) {
      int s = sl[wv][e];
      float4 q = pl[wv][e];
      ushort4 hv = *(const ushort4*)&hb[(size_t)s * 256 + lane * 4];
      acc0 += q.x * bf2f(hv.x);
      acc1 += q.y * bf2f(hv.y);
      acc2 += q.z * bf2f(hv.z);
      acc3 += q.w * bf2f(hv.w);
    }
  }
#pragma unroll
  for (int off = 32; off > 0; off >>= 1) {
    ds0 += __shfl_xor(ds0, off, 64);
    ds1 += __shfl_xor(ds1, off, 64);
    ds2 += __shfl_xor(ds2, off, 64);
    ds3 += __shfl_xor(ds3, off, 64);
  }
  float v[4];
  v[0] = fmaxf(acc0 / (ds0 + 1e-16f) + b1[lane], 0.f);
  v[1] = fmaxf(acc1 / (ds1 + 1e-16f) + b1[64 + lane], 0.f);
  v[2] = fmaxf(acc2 / (ds2 + 1e-16f) + b1[128 + lane], 0.f);
  v[3] = fmaxf(acc3 / (ds3 + 1e-16f) + b1[192 + lane], 0.f);
#pragma unroll
  for (int h = 0; h < 4; ++h) {
    ushort hi = f2bf(v[h]);
    ushort lo = f2bf(v[h] - bf2f(hi));
    A2[ab + h * 64 + lane] = hi;
    A2[ab + 256 + h * 64 + lane] = lo;
  }
}

// ---------------- aggregation layer 2 ----------------------------------------
__global__ __launch_bounds__(256) void agg2_kernel(const ushort* __restrict__ h2b,
    const float* __restrict__ as2, const float* __restrict__ ad2,
    const int* __restrict__ offsets, const int* __restrict__ src_sorted,
    const float* __restrict__ b2, float* __restrict__ out, int N) {
  __shared__ float pl[4][64];
  __shared__ alignas(16) int sl[4][64];
  int wv = threadIdx.x >> 6;
  int wid = (blockIdx.x << 2) + wv;
  int lane = threadIdx.x & 63;
  if (wid >= N) return;
  float ah = ad2[wid];
  int st = offsets[wid], en = offsets[wid + 1];
  float acc = 0.f, ds = 0.f;
  for (int c = st; c < en; c += 64) {
    int mye = c + lane;
    float p = 0.f;
    int smy = 0;
    if (mye < en) {
      smy = src_sorted[mye];
      p = __expf(lrelu(as2[smy] + ah));
    }
    ds += p;
    pl[wv][lane] = p;
    sl[wv][lane] = smy;
    int cnt = min(64, en - c);
    int e = 0;
    for (; e + 4 <= cnt; e += 4) {
      int4 s4 = *(const int4*)&sl[wv][e];
      float4 q4 = *(const float4*)&pl[wv][e];
      ushort h0 = h2b[(size_t)s4.x * 64 + lane];
      ushort h1 = h2b[(size_t)s4.y * 64 + lane];
      ushort h2 = h2b[(size_t)s4.z * 64 + lane];
      ushort h3 = h2b[(size_t)s4.w * 64 + lane];
      acc += q4.x * bf2f(h0) + q4.y * bf2f(h1) + q4.z * bf2f(h2) + q4.w * bf2f(h3);
    }
    for (; e < cnt; ++e) {
      acc += pl[wv][e] * bf2f(h2b[(size_t)sl[wv][e] * 64 + lane]);
    }
  }
#pragma unroll
  for (int off = 32; off > 0; off >>= 1) ds += __shfl_xor(ds, off, 64);
  out[(size_t)wid * 64 + lane] = acc / (ds + 1e-16f) + b2[lane];
}

// ---------------- launch ----------------
extern "C" void kernel_launch(void* const* d_in, const int* in_sizes, int n_in,
                              void* d_out, int out_size, void* d_ws, size_t ws_size,
                              hipStream_t stream) {
  const float* x      = (const float*)d_in[0];
  const int*   ei     = (const int*)d_in[1];
  const float* W1     = (const float*)d_in[2];
  const float* a_src1 = (const float*)d_in[3];
  const float* a_dst1 = (const float*)d_in[4];
  const float* b1     = (const float*)d_in[5];
  const float* W2     = (const float*)d_in[6];
  const float* a_src2 = (const float*)d_in[7];
  const float* a_dst2 = (const float*)d_in[8];
  const float* b2     = (const float*)d_in[9];
  float* out = (float*)d_out;

  const int IN = 256, HD = 256, D2 = 64;
  const int N = in_sizes[0] / IN;
  const int E = in_sizes[1] / 2;
  const int Etot = E + N;
  const int Mpad = ((N + 127) / 128) * 128;
  const int* srcp = ei;
  const int* dstp = ei + E;

  uintptr_t base = (uintptr_t)d_ws;
  auto alloc_bytes = [&](size_t nbytes) -> void* {
    void* p = (void*)base;
    base += (nbytes + 255) & ~(size_t)255;
    return p;
  };
  ushort* A1       = (ushort*)alloc_bytes((size_t)Mpad * 512 * 2);
  ushort* A2       = (ushort*)alloc_bytes((size_t)Mpad * 512 * 2);
  ushort* h1b      = (ushort*)alloc_bytes((size_t)N * HD * 2);
  ushort* h2b      = (ushort*)alloc_bytes((size_t)N * D2 * 2);
  ushort* B1t      = (ushort*)alloc_bytes((size_t)HD * 768 * 2);
  ushort* B2t      = (ushort*)alloc_bytes((size_t)D2 * 768 * 2);
  float* as1       = (float*)alloc_bytes((size_t)N * 4 * 4);
  float* ad1       = (float*)alloc_bytes((size_t)N * 4 * 4);
  // zero-init region start
  float* as2       = (float*)alloc_bytes((size_t)N * 4);
  float* ad2       = (float*)alloc_bytes((size_t)N * 4);
  int* counts      = (int*)alloc_bytes((size_t)(N + 1) * 4);
  uintptr_t zero_end = base;
  // zero-init region end
  int* cursor      = (int*)alloc_bytes((size_t)N * 4);
  int* offsets     = (int*)alloc_bytes((size_t)(N + 1) * 4);
  int* src_sorted  = (int*)alloc_bytes((size_t)Etot * 4);
  int* bsums       = (int*)alloc_bytes(256 * 4);
  int* bbase       = (int*)alloc_bytes(256 * 4);

  hipMemsetAsync((void*)as2, 0, zero_end - (uintptr_t)as2, stream);

  const int nwb  = (N + 3) / 4;
  const int nwbp = (Mpad + 3) / 4;
  const int neb  = (Etot + 255) / 256;
  const int nsb  = (N + SCB - 1) / SCB;

  // packing
  pack_x_kernel<<<(Mpad * 256 + 255) / 256, 256, 0, stream>>>(x, A1, N, Mpad);
  pack_w_kernel<<<(256 * HD + 255) / 256, 256, 0, stream>>>(W1, B1t, HD);
  pack_w_kernel<<<(256 * D2 + 255) / 256, 256, 0, stream>>>(W2, B2t, D2);
  // CSR (independent of layer 1)
  hist_kernel<<<neb, 256, 0, stream>>>(dstp, counts, E, Etot);
  scan1_kernel<<<nsb, 256, 0, stream>>>(counts, offsets, bsums, N);
  scan2_kernel<<<1, 256, 0, stream>>>(bsums, bbase, nsb);
  scan3_kernel<<<nsb, 256, 0, stream>>>(offsets, cursor, bbase, N, Etot);
  scatter_kernel<<<neb, 256, 0, stream>>>(srcp, dstp, cursor, src_sorted, E, Etot);
  // layer 1
  gemm_mfma<128, 4, true><<<dim3(HD / 128, Mpad / 128), 256, 0, stream>>>(
      A1, B1t, a_src1, a_dst1, h1b, as1, ad1, N, HD);
  agg1_kernel<<<nwbp, 256, 0, stream>>>(h1b, as1, ad1, offsets, src_sorted, b1, A2, N, Mpad);
  // layer 2
  gemm_mfma<64, 2, false><<<dim3(D2 / 64, Mpad / 128), 256, 0, stream>>>(
      A2, B2t, a_src2, a_dst2, h2b, as2, ad2, N, D2);
  agg2_kernel<<<nwb, 256, 0, stream>>>(h2b, as2, ad2, offsets, src_sorted, b2, out, N);
}

// Round 7
// 283.887 us; speedup vs baseline: 2.3598x; 1.0564x over previous
//
#include <hip/hip_runtime.h>
#include <hip/hip_bf16.h>

typedef __attribute__((ext_vector_type(8))) short short8v;
typedef __attribute__((ext_vector_type(4))) float f32x4;

// ---------------- helpers ----------------
__device__ __forceinline__ float lrelu(float x) { return x > 0.f ? x : 0.2f * x; }
__device__ __forceinline__ ushort f2bf(float v) {
  __hip_bfloat16 b = __float2bfloat16(v);
  return *(ushort*)&b;
}
__device__ __forceinline__ float bf2f(ushort u) {
  return __uint_as_float(((unsigned)u) << 16);
}
__device__ __forceinline__ void gload16(const ushort* g, ushort* l) {
  __builtin_amdgcn_global_load_lds((const __attribute__((address_space(1))) void*)g,
                                   (__attribute__((address_space(3))) void*)l, 16, 0, 0);
}

// ---------------- pack kernels ----------------
// A1: plain bf16 [Mpad][256] (x quantized; err negligible since W is 0.06-scale)
__global__ __launch_bounds__(256) void pack_x_kernel(const float* __restrict__ x,
    ushort* __restrict__ A, int N, int Mpad) {
  int idx = blockIdx.x * 256 + threadIdx.x;
  if (idx >= Mpad * 256) return;
  int row = idx >> 8, c = idx & 255;
  float v = (row < N) ? x[idx] : 0.f;
  A[(size_t)row * 256 + c] = f2bf(v);
}

// Bt layout: [NN][512] bf16, k in [0,256)=hi(W), [256,512)=lo(W).
// Pairs with A (k-folded: k>=256 re-reads A's [0,256)) -> A*hi + A*lo.
__global__ __launch_bounds__(256) void pack_w_kernel(const float* __restrict__ W,
    ushort* __restrict__ Bt, int NN) {
  int idx = blockIdx.x * 256 + threadIdx.x;  // over 256*NN, W is [256][NN]
  if (idx >= 256 * NN) return;
  int k = idx / NN, col = idx % NN;
  float v = W[idx];
  ushort hi = f2bf(v), lo = f2bf(v - bf2f(hi));
  size_t b = (size_t)col * 512;
  Bt[b + k] = hi;
  Bt[b + 256 + k] = lo;
}

// ---------------- MFMA GEMM with fused bf16-output + attention dots ----------
// A: [Mpad][KAT] bf16, Bt: [NN][KT] bf16 (B transposed). KT=512, KAT=256:
// k-fold re-reads A for the lo(W) half.
// IL=true: Hb written interleaved as [row][feat*4 + head] (NN=256, 4 heads).
template<int BN, int NF, bool IL, int KT, int KAT>
__global__ __launch_bounds__(256) void gemm_mfma(
    const ushort* __restrict__ A, const ushort* __restrict__ Bt,
    const float* __restrict__ avs, const float* __restrict__ avd,
    ushort* __restrict__ Hb, float* __restrict__ os, float* __restrict__ od,
    int M, int NN) {
  constexpr int BM = 128, BK = 64;
  __shared__ ushort As[BM * BK];
  __shared__ ushort Bs[BN * BK];
  const int t = threadIdx.x, l = t & 63, w = t >> 6;
  const int l15 = l & 15, l4 = l >> 4;
  const int m0 = blockIdx.y * BM, n0 = blockIdx.x * BN;
  const int wr = w >> 1, wc = w & 1;
  f32x4 acc[4][NF];
#pragma unroll
  for (int m = 0; m < 4; ++m)
#pragma unroll
    for (int n = 0; n < NF; ++n) acc[m][n] = (f32x4){0.f, 0.f, 0.f, 0.f};

  for (int kk = 0; kk < KT; kk += BK) {
    const int ka = (kk < KAT) ? kk : kk - KAT;
    __syncthreads();
#pragma unroll
    for (int i = 0; i < 4; ++i) {  // A tile: 16 wave-chunks of 1KB
      int q = w * 4 + i;
      int c = q * 64 + l;
      int row = c >> 3, k8 = c & 7;
      int k8s = k8 ^ (row & 7);
      gload16(&A[(size_t)(m0 + row) * KAT + ka + k8s * 8], &As[q * 512]);
    }
    constexpr int BCHW = (BN * 8 / 64) / 4;
#pragma unroll
    for (int i = 0; i < BCHW; ++i) {
      int q = w * BCHW + i;
      int c = q * 64 + l;
      int col = c >> 3, k8 = c & 7;
      int k8s = k8 ^ (col & 7);
      gload16(&Bt[(size_t)(n0 + col) * KT + kk + k8s * 8], &Bs[q * 512]);
    }
    __syncthreads();
#pragma unroll
    for (int ks = 0; ks < 2; ++ks) {
      int kb = ks * 4 + l4;
      short8v af[4], bfr[NF];
#pragma unroll
      for (int m = 0; m < 4; ++m) {
        int row = wr * 64 + m * 16 + l15;
        af[m] = *(const short8v*)&As[row * 64 + (kb ^ (row & 7)) * 8];
      }
#pragma unroll
      for (int n = 0; n < NF; ++n) {
        int col = wc * (NF * 16) + n * 16 + l15;
        bfr[n] = *(const short8v*)&Bs[col * 64 + (kb ^ (col & 7)) * 8];
      }
#pragma unroll
      for (int m = 0; m < 4; ++m)
#pragma unroll
        for (int n = 0; n < NF; ++n)
          acc[m][n] = __builtin_amdgcn_mfma_f32_16x16x32_bf16(af[m], bfr[n], acc[m][n], 0, 0, 0);
    }
  }
  // ---- epilogue: bf16 output copy ----
#pragma unroll
  for (int m = 0; m < 4; ++m) {
    int rbase = m0 + wr * 64 + m * 16 + l4 * 4;
#pragma unroll
    for (int n = 0; n < NF; ++n) {
      int c = wc * (NF * 16) + n * 16 + l15;  // block-local col
      int gcol = IL ? (((n0 + c) & 63) * 4 + ((n0 + c) >> 6)) : (n0 + c);
#pragma unroll
      for (int r = 0; r < 4; ++r) {
        int row = rbase + r;
        if (row < M) Hb[(size_t)row * NN + gcol] = f2bf(acc[m][n][r]);
      }
    }
  }
  // ---- epilogue: attention dots ----
  float cs[NF], cd[NF];
#pragma unroll
  for (int n = 0; n < NF; ++n) {
    int gc = n0 + wc * (NF * 16) + n * 16 + l15;
    cs[n] = avs[gc];
    cd[n] = avd[gc];
  }
  const int H = NN >> 6;
  const int head = (n0 + wc * (NF * 16)) >> 6;
#pragma unroll
  for (int m = 0; m < 4; ++m) {
#pragma unroll
    for (int r = 0; r < 4; ++r) {
      float ps = 0.f, pd = 0.f;
#pragma unroll
      for (int n = 0; n < NF; ++n) { ps += acc[m][n][r] * cs[n]; pd += acc[m][n][r] * cd[n]; }
#pragma unroll
      for (int off = 1; off < 16; off <<= 1) {
        ps += __shfl_xor(ps, off, 64);
        pd += __shfl_xor(pd, off, 64);
      }
      if (l15 == 0) {
        int row = m0 + wr * 64 + m * 16 + l4 * 4 + r;
        if (row < M) {
          if (NF == 4) {
            os[(size_t)row * H + head] = ps;
            od[(size_t)row * H + head] = pd;
          } else {
            atomicAdd(&os[row], ps);
            atomicAdd(&od[row], pd);
          }
        }
      }
    }
  }
}

// ---------------- CSR build ----------------
__global__ void hist_kernel(const int* __restrict__ dst, int* __restrict__ counts,
                            int E, int Etot) {
  int e = blockIdx.x * blockDim.x + threadIdx.x;
  if (e >= Etot) return;
  int d = (e < E) ? dst[e] : (e - E);
  atomicAdd(&counts[d], 1);
}

// hierarchical scan: 2048 elems/block, coalesced, 3 tiny phases
static constexpr int SCB = 2048;

__global__ __launch_bounds__(256) void scan1_kernel(const int* __restrict__ counts,
    int* __restrict__ offsets, int* __restrict__ bsums, int n) {
  __shared__ int wsum[4];
  int t = threadIdx.x, lane = t & 63, w = t >> 6;
  int base = blockIdx.x * SCB + t * 8;
  int c[8];
  if (base + 7 < n) {
    int4 v0 = *(const int4*)&counts[base];
    int4 v1 = *(const int4*)&counts[base + 4];
    c[0] = v0.x; c[1] = v0.y; c[2] = v0.z; c[3] = v0.w;
    c[4] = v1.x; c[5] = v1.y; c[6] = v1.z; c[7] = v1.w;
  } else {
#pragma unroll
    for (int j = 0; j < 8; ++j) c[j] = (base + j < n) ? counts[base + j] : 0;
  }
  int ts = 0;
#pragma unroll
  for (int j = 0; j < 8; ++j) ts += c[j];
  int x = ts;
#pragma unroll
  for (int off = 1; off < 64; off <<= 1) {
    int y = __shfl_up(x, off, 64);
    if (lane >= off) x += y;
  }
  if (lane == 63) wsum[w] = x;
  __syncthreads();
  int wpre = 0;
  for (int ww = 0; ww < w; ++ww) wpre += wsum[ww];
  int ex = wpre + x - ts;  // exclusive prefix of this thread's first elem
  int o[8];
#pragma unroll
  for (int j = 0; j < 8; ++j) { o[j] = ex; ex += c[j]; }
  if (base + 7 < n) {
    *(int4*)&offsets[base] = make_int4(o[0], o[1], o[2], o[3]);
    *(int4*)&offsets[base + 4] = make_int4(o[4], o[5], o[6], o[7]);
  } else {
#pragma unroll
    for (int j = 0; j < 8; ++j) if (base + j < n) offsets[base + j] = o[j];
  }
  if (t == 255) bsums[blockIdx.x] = wpre + x;
}

__global__ __launch_bounds__(256) void scan2_kernel(const int* __restrict__ bsums,
    int* __restrict__ bbase, int nb) {
  __shared__ int wsum[4];
  int t = threadIdx.x, lane = t & 63, w = t >> 6;
  int v = (t < nb) ? bsums[t] : 0;
  int x = v;
#pragma unroll
  for (int off = 1; off < 64; off <<= 1) {
    int y = __shfl_up(x, off, 64);
    if (lane >= off) x += y;
  }
  if (lane == 63) wsum[w] = x;
  __syncthreads();
  int wpre = 0;
  for (int ww = 0; ww < w; ++ww) wpre += wsum[ww];
  if (t < nb) bbase[t] = wpre + x - v;
}

__global__ __launch_bounds__(256) void scan3_kernel(int* __restrict__ offsets,
    int* __restrict__ cursor, const int* __restrict__ bbase, int n, int total) {
  int t = threadIdx.x;
  int bb = bbase[blockIdx.x];
  int base = blockIdx.x * SCB + t * 8;
  if (base + 7 < n) {
    int4 v0 = *(const int4*)&offsets[base];
    int4 v1 = *(const int4*)&offsets[base + 4];
    v0.x += bb; v0.y += bb; v0.z += bb; v0.w += bb;
    v1.x += bb; v1.y += bb; v1.z += bb; v1.w += bb;
    *(int4*)&offsets[base] = v0;
    *(int4*)&offsets[base + 4] = v1;
    *(int4*)&cursor[base] = v0;
    *(int4*)&cursor[base + 4] = v1;
  } else {
#pragma unroll
    for (int j = 0; j < 8; ++j)
      if (base + j < n) {
        int vv = offsets[base + j] + bb;
        offsets[base + j] = vv;
        cursor[base + j] = vv;
      }
  }
  if (blockIdx.x == 0 && t == 0) offsets[n] = total;
}

__global__ void scatter_kernel(const int* __restrict__ src, const int* __restrict__ dst,
    int* __restrict__ cursor, int* __restrict__ src_sorted, int E, int Etot) {
  int e = blockIdx.x * blockDim.x + threadIdx.x;
  if (e >= Etot) return;
  int s = (e < E) ? src[e] : (e - E);
  int d = (e < E) ? dst[e] : (e - E);
  int pos = atomicAdd(&cursor[d], 1);
  src_sorted[pos] = s;
}

// ---------------- aggregation layer 1 ----------------------------------------
// h1b interleaved: [row][feat*4 + head]. Per 64-edge chunk: lane-parallel p
// computation staged to LDS, then 8x-unrolled gather loop (uniform-address LDS
// broadcasts for p/src, 8 independent row loads in flight).
__global__ __launch_bounds__(256) void agg1_kernel(const ushort* __restrict__ h1b,
    const float* __restrict__ as1, const float* __restrict__ ad1,
    const int* __restrict__ offsets, const int* __restrict__ src_sorted,
    const float* __restrict__ b1, ushort* __restrict__ A2, int N, int Mpad) {
  __shared__ float4 pl[4][64];
  __shared__ alignas(16) int sl[4][64];
  int wv = threadIdx.x >> 6;
  int wid = (blockIdx.x << 2) + wv;
  int lane = threadIdx.x & 63;
  if (wid >= Mpad) return;
  size_t ab = (size_t)wid * 256;
  if (wid >= N) {
#pragma unroll
    for (int i = 0; i < 4; ++i) A2[ab + i * 64 + lane] = 0;
    return;
  }
  float4 ah = *(const float4*)&ad1[(size_t)wid * 4];
  int st = offsets[wid], en = offsets[wid + 1];
  float acc0 = 0.f, acc1 = 0.f, acc2 = 0.f, acc3 = 0.f;
  float ds0 = 0.f, ds1 = 0.f, ds2 = 0.f, ds3 = 0.f;
  const ushort* __restrict__ hb = h1b;
  const int lo4 = lane * 4;
  for (int c = st; c < en; c += 64) {
    int mye = c + lane;
    float4 p = make_float4(0.f, 0.f, 0.f, 0.f);
    int smy = 0;
    if (mye < en) {
      smy = src_sorted[mye];
      float4 a4 = *(const float4*)&as1[(size_t)smy * 4];
      p.x = __expf(lrelu(a4.x + ah.x));
      p.y = __expf(lrelu(a4.y + ah.y));
      p.z = __expf(lrelu(a4.z + ah.z));
      p.w = __expf(lrelu(a4.w + ah.w));
    }
    ds0 += p.x; ds1 += p.y; ds2 += p.z; ds3 += p.w;
    pl[wv][lane] = p;
    sl[wv][lane] = smy;
    int cnt = min(64, en - c);
    int e = 0;
    for (; e + 8 <= cnt; e += 8) {
      int4 sa = *(const int4*)&sl[wv][e];       // uniform addr -> broadcast
      int4 sb = *(const int4*)&sl[wv][e + 4];
      ushort4 h0 = *(const ushort4*)&hb[(size_t)sa.x * 256 + lo4];
      ushort4 h1 = *(const ushort4*)&hb[(size_t)sa.y * 256 + lo4];
      ushort4 h2 = *(const ushort4*)&hb[(size_t)sa.z * 256 + lo4];
      ushort4 h3 = *(const ushort4*)&hb[(size_t)sa.w * 256 + lo4];
      ushort4 h4 = *(const ushort4*)&hb[(size_t)sb.x * 256 + lo4];
      ushort4 h5 = *(const ushort4*)&hb[(size_t)sb.y * 256 + lo4];
      ushort4 h6 = *(const ushort4*)&hb[(size_t)sb.z * 256 + lo4];
      ushort4 h7 = *(const ushort4*)&hb[(size_t)sb.w * 256 + lo4];
      float4 q0 = pl[wv][e + 0];
      float4 q1 = pl[wv][e + 1];
      float4 q2 = pl[wv][e + 2];
      float4 q3 = pl[wv][e + 3];
      float4 q4 = pl[wv][e + 4];
      float4 q5 = pl[wv][e + 5];
      float4 q6 = pl[wv][e + 6];
      float4 q7 = pl[wv][e + 7];
      acc0 += q0.x * bf2f(h0.x); acc1 += q0.y * bf2f(h0.y);
      acc2 += q0.z * bf2f(h0.z); acc3 += q0.w * bf2f(h0.w);
      acc0 += q1.x * bf2f(h1.x); acc1 += q1.y * bf2f(h1.y);
      acc2 += q1.z * bf2f(h1.z); acc3 += q1.w * bf2f(h1.w);
      acc0 += q2.x * bf2f(h2.x); acc1 += q2.y * bf2f(h2.y);
      acc2 += q2.z * bf2f(h2.z); acc3 += q2.w * bf2f(h2.w);
      acc0 += q3.x * bf2f(h3.x); acc1 += q3.y * bf2f(h3.y);
      acc2 += q3.z * bf2f(h3.z); acc3 += q3.w * bf2f(h3.w);
      acc0 += q4.x * bf2f(h4.x); acc1 += q4.y * bf2f(h4.y);
      acc2 += q4.z * bf2f(h4.z); acc3 += q4.w * bf2f(h4.w);
      acc0 += q5.x * bf2f(h5.x); acc1 += q5.y * bf2f(h5.y);
      acc2 += q5.z * bf2f(h5.z); acc3 += q5.w * bf2f(h5.w);
      acc0 += q6.x * bf2f(h6.x); acc1 += q6.y * bf2f(h6.y);
      acc2 += q6.z * bf2f(h6.z); acc3 += q6.w * bf2f(h6.w);
      acc0 += q7.x * bf2f(h7.x); acc1 += q7.y * bf2f(h7.y);
      acc2 += q7.z * bf2f(h7.z); acc3 += q7.w * bf2f(h7.w);
    }
    for (; e < cnt; ++e) {
      int s = sl[wv][e];
      float4 q = pl[wv][e];
      ushort4 hv = *(const ushort4*)&hb[(size_t)s * 256 + lo4];
      acc0 += q.x * bf2f(hv.x);
      acc1 += q.y * bf2f(hv.y);
      acc2 += q.z * bf2f(hv.z);
      acc3 += q.w * bf2f(hv.w);
    }
  }
#pragma unroll
  for (int off = 32; off > 0; off >>= 1) {
    ds0 += __shfl_xor(ds0, off, 64);
    ds1 += __shfl_xor(ds1, off, 64);
    ds2 += __shfl_xor(ds2, off, 64);
    ds3 += __shfl_xor(ds3, off, 64);
  }
  float v[4];
  v[0] = fmaxf(acc0 / (ds0 + 1e-16f) + b1[lane], 0.f);
  v[1] = fmaxf(acc1 / (ds1 + 1e-16f) + b1[64 + lane], 0.f);
  v[2] = fmaxf(acc2 / (ds2 + 1e-16f) + b1[128 + lane], 0.f);
  v[3] = fmaxf(acc3 / (ds3 + 1e-16f) + b1[192 + lane], 0.f);
#pragma unroll
  for (int h = 0; h < 4; ++h) A2[ab + h * 64 + lane] = f2bf(v[h]);
}

// ---------------- aggregation layer 2 ----------------------------------------
__global__ __launch_bounds__(256) void agg2_kernel(const ushort* __restrict__ h2b,
    const float* __restrict__ as2, const float* __restrict__ ad2,
    const int* __restrict__ offsets, const int* __restrict__ src_sorted,
    const float* __restrict__ b2, float* __restrict__ out, int N) {
  __shared__ float pl[4][64];
  __shared__ alignas(16) int sl[4][64];
  int wv = threadIdx.x >> 6;
  int wid = (blockIdx.x << 2) + wv;
  int lane = threadIdx.x & 63;
  if (wid >= N) return;
  float ah = ad2[wid];
  int st = offsets[wid], en = offsets[wid + 1];
  float acc = 0.f, ds = 0.f;
  for (int c = st; c < en; c += 64) {
    int mye = c + lane;
    float p = 0.f;
    int smy = 0;
    if (mye < en) {
      smy = src_sorted[mye];
      p = __expf(lrelu(as2[smy] + ah));
    }
    ds += p;
    pl[wv][lane] = p;
    sl[wv][lane] = smy;
    int cnt = min(64, en - c);
    int e = 0;
    for (; e + 8 <= cnt; e += 8) {
      int4 sa = *(const int4*)&sl[wv][e];
      int4 sb = *(const int4*)&sl[wv][e + 4];
      float4 qa = *(const float4*)&pl[wv][e];
      float4 qb = *(const float4*)&pl[wv][e + 4];
      ushort h0 = h2b[(size_t)sa.x * 64 + lane];
      ushort h1 = h2b[(size_t)sa.y * 64 + lane];
      ushort h2 = h2b[(size_t)sa.z * 64 + lane];
      ushort h3 = h2b[(size_t)sa.w * 64 + lane];
      ushort h4 = h2b[(size_t)sb.x * 64 + lane];
      ushort h5 = h2b[(size_t)sb.y * 64 + lane];
      ushort h6 = h2b[(size_t)sb.z * 64 + lane];
      ushort h7 = h2b[(size_t)sb.w * 64 + lane];
      acc += qa.x * bf2f(h0) + qa.y * bf2f(h1) + qa.z * bf2f(h2) + qa.w * bf2f(h3);
      acc += qb.x * bf2f(h4) + qb.y * bf2f(h5) + qb.z * bf2f(h6) + qb.w * bf2f(h7);
    }
    for (; e < cnt; ++e) {
      acc += pl[wv][e] * bf2f(h2b[(size_t)sl[wv][e] * 64 + lane]);
    }
  }
#pragma unroll
  for (int off = 32; off > 0; off >>= 1) ds += __shfl_xor(ds, off, 64);
  out[(size_t)wid * 64 + lane] = acc / (ds + 1e-16f) + b2[lane];
}

// ---------------- launch ----------------
extern "C" void kernel_launch(void* const* d_in, const int* in_sizes, int n_in,
                              void* d_out, int out_size, void* d_ws, size_t ws_size,
                              hipStream_t stream) {
  const float* x      = (const float*)d_in[0];
  const int*   ei     = (const int*)d_in[1];
  const float* W1     = (const float*)d_in[2];
  const float* a_src1 = (const float*)d_in[3];
  const float* a_dst1 = (const float*)d_in[4];
  const float* b1     = (const float*)d_in[5];
  const float* W2     = (const float*)d_in[6];
  const float* a_src2 = (const float*)d_in[7];
  const float* a_dst2 = (const float*)d_in[8];
  const float* b2     = (const float*)d_in[9];
  float* out = (float*)d_out;

  const int IN = 256, HD = 256, D2 = 64;
  const int N = in_sizes[0] / IN;
  const int E = in_sizes[1] / 2;
  const int Etot = E + N;
  const int Mpad = ((N + 127) / 128) * 128;
  const int* srcp = ei;
  const int* dstp = ei + E;

  uintptr_t base = (uintptr_t)d_ws;
  auto alloc_bytes = [&](size_t nbytes) -> void* {
    void* p = (void*)base;
    base += (nbytes + 255) & ~(size_t)255;
    return p;
  };
  ushort* A1       = (ushort*)alloc_bytes((size_t)Mpad * 256 * 2);
  ushort* A2       = (ushort*)alloc_bytes((size_t)Mpad * 256 * 2);
  ushort* h1b      = (ushort*)alloc_bytes((size_t)N * HD * 2);
  ushort* h2b      = (ushort*)alloc_bytes((size_t)N * D2 * 2);
  ushort* B1t      = (ushort*)alloc_bytes((size_t)HD * 512 * 2);
  ushort* B2t      = (ushort*)alloc_bytes((size_t)D2 * 512 * 2);
  float* as1       = (float*)alloc_bytes((size_t)N * 4 * 4);
  float* ad1       = (float*)alloc_bytes((size_t)N * 4 * 4);
  // zero-init region start
  float* as2       = (float*)alloc_bytes((size_t)N * 4);
  float* ad2       = (float*)alloc_bytes((size_t)N * 4);
  int* counts      = (int*)alloc_bytes((size_t)(N + 1) * 4);
  uintptr_t zero_end = base;
  // zero-init region end
  int* cursor      = (int*)alloc_bytes((size_t)N * 4);
  int* offsets     = (int*)alloc_bytes((size_t)(N + 1) * 4);
  int* src_sorted  = (int*)alloc_bytes((size_t)Etot * 4);
  int* bsums       = (int*)alloc_bytes(256 * 4);
  int* bbase       = (int*)alloc_bytes(256 * 4);

  hipMemsetAsync((void*)as2, 0, zero_end - (uintptr_t)as2, stream);

  const int nwb  = (N + 3) / 4;
  const int nwbp = (Mpad + 3) / 4;
  const int neb  = (Etot + 255) / 256;
  const int nsb  = (N + SCB - 1) / SCB;

  // packing
  pack_x_kernel<<<(Mpad * 256 + 255) / 256, 256, 0, stream>>>(x, A1, N, Mpad);
  pack_w_kernel<<<(256 * HD + 255) / 256, 256, 0, stream>>>(W1, B1t, HD);
  pack_w_kernel<<<(256 * D2 + 255) / 256, 256, 0, stream>>>(W2, B2t, D2);
  // CSR (independent of layer 1)
  hist_kernel<<<neb, 256, 0, stream>>>(dstp, counts, E, Etot);
  scan1_kernel<<<nsb, 256, 0, stream>>>(counts, offsets, bsums, N);
  scan2_kernel<<<1, 256, 0, stream>>>(bsums, bbase, nsb);
  scan3_kernel<<<nsb, 256, 0, stream>>>(offsets, cursor, bbase, N, Etot);
  scatter_kernel<<<neb, 256, 0, stream>>>(srcp, dstp, cursor, src_sorted, E, Etot);
  // layer 1
  gemm_mfma<128, 4, true, 512, 256><<<dim3(HD / 128, Mpad / 128), 256, 0, stream>>>(
      A1, B1t, a_src1, a_dst1, h1b, as1, ad1, N, HD);
  agg1_kernel<<<nwbp, 256, 0, stream>>>(h1b, as1, ad1, offsets, src_sorted, b1, A2, N, Mpad);
  // layer 2
  gemm_mfma<64, 2, false, 512, 256><<<dim3(D2 / 64, Mpad / 128), 256, 0, stream>>>(
      A2, B2t, a_src2, a_dst2, h2b, as2, ad2, N, D2);
  agg2_kernel<<<nwb, 256, 0, stream>>>(h2b, as2, ad2, offsets, src_sorted, b2, out, N);
}